// Round 14
// baseline (107.647 us; speedup 1.0000x reference)
//
#include <hip/hip_runtime.h>
#include <hip/hip_fp16.h>
#include <math.h>

#define B_    8
#define S_    8192
#define DIN   64
#define DM    256
#define NS    32
#define NL    4
#define TOUT  64
#define NWARM 64
#define PIPE  128            // 64 warm + 64 out
#define HIST  16             // scan window; a^17 ~ 7e-9
#define NBLK  1024           // B_*S_/TOUT
#define NTHR  256            // 4 waves; 2 Mtiles (32 tokens) per wave

// ---- fp32 precomputed-weight offsets (Wf) ----
#define OFF_G   0
#define OFF_GX  4096
#define OFF_G0  4160
#define OFF_WY  4224
#define OFF_WU  12416
#define OFF_P   20608
#define OFF_R   26752
#define OFF_CY  36992
#define OFF_CU  37120
#define OFF_TX  37248
#define OFF_TV  37504
#define OFF_CT  37824
#define OFF_CC  37828
#define OFF_AV  37832
#define PRE_N   37960

// ---- frag buffer (u32 units). 72 frag-units of 256 u32 + TX/TV tails ----
#define TXOFF  18432         // 4*32 u32
#define TVOFF  18560         // 10*16 u32
#define WS_FRAG 40960        // float offset of Fr in ws
#define WS_PART 65536        // float offset of part[1024][193]

// ---- LDS u32 layout. x[128][34] (init-only) overlays SLOT+SCR. ----
#define SLOT  0              // scan slot [128][17], reused by all layers
#define SCR_S 2176           // 256 floats (endgame s scratch)
#define SCR_X 2432           // 128 floats (endgame x scratch)
#define LNQ   4352           // float[128]
#define LTL   4480           // float[128] (tl; reused as r at end)
#define LDSN  4608           // 18,432 B

typedef _Float16 h2_t  __attribute__((ext_vector_type(2)));
typedef _Float16 f16x8 __attribute__((ext_vector_type(8)));
typedef float    f32x4 __attribute__((ext_vector_type(4)));
typedef uint     uv4   __attribute__((ext_vector_type(4)));

__device__ __forceinline__ float h2f(ushort u) { return __half2float(__ushort_as_half(u)); }
__device__ __forceinline__ ushort f2h(float f) { return __half_as_ushort(__float2half(f)); }
__device__ __forceinline__ uint pack2(float a, float b) {
  return (uint)f2h(a) | ((uint)f2h(b) << 16);
}
__device__ __forceinline__ void unpack2(uint w, float& a, float& b) {
  a = h2f((ushort)(w & 0xffffu)); b = h2f((ushort)(w >> 16));
}
__device__ __forceinline__ float fdot2h(uint w, uint v, float c) {
  return __builtin_amdgcn_fdot2(__builtin_bit_cast(h2_t, w),
                                __builtin_bit_cast(h2_t, v), c, false);
}
__device__ __forceinline__ f32x4 MF(uv4 a, uv4 b, f32x4 c) {
  return __builtin_amdgcn_mfma_f32_16x16x32_f16(
      __builtin_bit_cast(f16x8, a), __builtin_bit_cast(f16x8, b), c, 0, 0, 0);
}
__device__ __forceinline__ uv4 ldB(const uint* __restrict__ Fr, int unit, int lane) {
  return ((const uv4*)Fr)[unit * 64 + lane];
}

// ---------------------------------------------------------------------------
// Prep: fused fp32 matrices + direct fp16 fragment packing.
// 8 lanes per output (32 d-iters each) + intra-octet shfl reduce.
// ---------------------------------------------------------------------------
__global__ void ssm_prep(const float* __restrict__ in_w, const float* __restrict__ in_b,
                         const float* __restrict__ logA,
                         const float* __restrict__ Bw, const float* __restrict__ Cw,
                         const float* __restrict__ Cb, const float* __restrict__ nsc,
                         float* __restrict__ Wf, ushort* __restrict__ FrH)
{
  const int gid = blockIdx.x * 256 + threadIdx.x;
  const int t = gid >> 3, piece = gid & 7;
  if (t >= PRE_N) return;
  const int d0 = piece * 32, d1 = d0 + 32;
  const int pm6[6]  = {1,2,2,3,3,3}, pl6[6] = {0,0,1,0,1,2};
  const int rm10[10] = {0,1,1,2,2,2,3,3,3,3}, rl10[10] = {0,0,1,0,1,2,0,1,2,3};
  float s = 0.f;
  if (t < OFF_GX) {
    const int i = t >> 6, jj = t & 63;
    for (int d = d0; d < d1; ++d) s = fmaf(in_w[d*64 + i], in_w[d*64 + jj], s);
  } else if (t < OFF_G0) {
    const int i = t - OFF_GX;
    for (int d = d0; d < d1; ++d) s = fmaf(in_w[d*64 + i], in_b[d], s);
  } else if (t < OFF_WY) {
    if (t == OFF_G0) { for (int d = d0; d < d1; ++d) s = fmaf(in_b[d], in_b[d], s); }
  } else if (t < OFF_WU) {
    const int r = t - OFF_WY, l = r >> 11, qq = r & 2047, c = qq >> 5, n = qq & 31;
    for (int d = d0; d < d1; ++d)
      s = fmaf(Bw[(l*NS + n)*DM + d] * nsc[l*DM + d], in_w[d*64 + c], s);
  } else if (t < OFF_P) {
    const int r = t - OFF_WU, l = r >> 11, qq = r & 2047, c = qq >> 5, n = qq & 31;
    for (int d = d0; d < d1; ++d)
      s = fmaf(Cw[(l*DM + d)*NS + n], in_w[d*64 + c], s);
  } else if (t < OFF_R) {
    const int r = t - OFF_P, pi = r >> 10, qq = r & 1023, np = qq >> 5, n = qq & 31;
    const int m = pm6[pi], lp = pl6[pi];
    for (int d = d0; d < d1; ++d)
      s = fmaf(Bw[(m*NS + n)*DM + d] * nsc[m*DM + d], Cw[(lp*DM + d)*NS + np], s);
  } else if (t < OFF_CY) {
    const int r = t - OFF_R, ri = r >> 10, qq = r & 1023, np = qq >> 5, n = qq & 31;
    const int m = rm10[ri], lp = rl10[ri];
    for (int d = d0; d < d1; ++d)
      s = fmaf(Cw[(m*DM + d)*NS + n], Cw[(lp*DM + d)*NS + np], s);
  } else if (t < OFF_CU) {
    const int r = t - OFF_CY, l = r >> 5, n = r & 31;
    for (int d = d0; d < d1; ++d) {
      float bs = in_b[d];
      for (int lp = 0; lp < l; ++lp) bs += Cb[lp*DM + d];
      s = fmaf(Bw[(l*NS + n)*DM + d] * nsc[l*DM + d], bs, s);
    }
  } else if (t < OFF_TX) {
    const int r = t - OFF_CU, l = r >> 5, n = r & 31;
    for (int d = d0; d < d1; ++d) {
      float bs = in_b[d];
      for (int lp = 0; lp < l; ++lp) bs += Cb[lp*DM + d];
      s = fmaf(Cw[(l*DM + d)*NS + n], bs, s);
    }
  } else if (t < OFF_TV) {
    const int r = t - OFF_TX, l = r >> 6, i = r & 63;
    for (int d = d0; d < d1; ++d) s = fmaf(Cb[l*DM + d], in_w[d*64 + i], s);
  } else if (t < OFF_CT) {
    const int r = t - OFF_TV, vi = r >> 5, np = r & 31;
    const int m = rm10[vi], lp = rl10[vi];
    for (int d = d0; d < d1; ++d)
      s = fmaf(Cb[m*DM + d], Cw[(lp*DM + d)*NS + np], s);
  } else if (t < OFF_CC) {
    const int l = t - OFF_CT;
    for (int d = d0; d < d1; ++d) {
      float bs = in_b[d];
      for (int lp = 0; lp < l; ++lp) bs += Cb[lp*DM + d];
      s = fmaf(Cb[l*DM + d], bs, s);
    }
  } else if (t < OFF_AV) {
    const int l = t - OFF_CC;
    for (int d = d0; d < d1; ++d) s = fmaf(Cb[l*DM + d], Cb[l*DM + d], s);
  } else {
    s = (piece == 0) ? 1.0f / (1.0f + expf(-logA[t - OFF_AV])) : 0.f;
  }
  s += __shfl_xor(s, 1, 64);
  s += __shfl_xor(s, 2, 64);
  s += __shfl_xor(s, 4, 64);
  if (piece != 0) return;
  Wf[t] = s;

  // ---- direct fragment packing ----
  if (t < OFF_GX) {                      // G [64][64]
    const int kk = t >> 6, n = t & 63;
    const int u = (kk >> 5)*4 + (n >> 4);
    const int lane = (((kk & 31) >> 3) << 4) + (n & 15);
    FrH[(u*256 + lane*4 + ((kk & 7) >> 1))*2 + (kk & 1)] = f2h(s);
  } else if (t >= OFF_WY && t < OFF_WU) {   // WY [4][64][32]
    const int r = t - OFF_WY, l = r >> 11, kk = (r & 2047) >> 5, n = r & 31;
    const int u = 8 + l*4 + (kk >> 5)*2 + (n >> 4);
    const int lane = (((kk & 31) >> 3) << 4) + (n & 15);
    FrH[(u*256 + lane*4 + ((kk & 7) >> 1))*2 + (kk & 1)] = f2h(s);
  } else if (t >= OFF_WU && t < OFF_P) {    // WU [4][64][32]
    const int r = t - OFF_WU, l = r >> 11, kk = (r & 2047) >> 5, n = r & 31;
    const int u = 24 + l*4 + (kk >> 5)*2 + (n >> 4);
    const int lane = (((kk & 31) >> 3) << 4) + (n & 15);
    FrH[(u*256 + lane*4 + ((kk & 7) >> 1))*2 + (kk & 1)] = f2h(s);
  } else if (t >= OFF_P && t < OFF_R) {     // P [6][32][32]
    const int r = t - OFF_P, pi = r >> 10, kk = (r & 1023) >> 5, n = r & 31;
    const int u = 40 + pi*2 + (n >> 4);
    const int lane = ((kk >> 3) << 4) + (n & 15);
    FrH[(u*256 + lane*4 + ((kk & 7) >> 1))*2 + (kk & 1)] = f2h(s);
  } else if (t >= OFF_R && t < OFF_CY) {    // R [10][32][32], self x0.5
    const int r = t - OFF_R, ri = r >> 10, kk = (r & 1023) >> 5, n = r & 31;
    const int u = 52 + ri*2 + (n >> 4);
    const int lane = ((kk >> 3) << 4) + (n & 15);
    const float sc = (ri == 0 || ri == 2 || ri == 5 || ri == 9) ? 0.5f : 1.f;
    FrH[(u*256 + lane*4 + ((kk & 7) >> 1))*2 + (kk & 1)] = f2h(s * sc);
  } else if (t >= OFF_TX && t < OFF_TV) {
    const int r = t - OFF_TX, l = r >> 6, i = r & 63;
    FrH[(TXOFF + l*32 + (i >> 1))*2 + (i & 1)] = f2h(s);
  } else if (t >= OFF_TV && t < OFF_CT) {
    const int r = t - OFF_TV, vi = r >> 5, nn = r & 31;
    FrH[(TVOFF + vi*16 + (nn >> 1))*2 + (nn & 1)] = f2h(s);
  }
}

// ---------------------------------------------------------------------------
// Per-layer body. Single reused scan slot; s saved per-lane in packed regs.
// ---------------------------------------------------------------------------
template<int L>
__device__ __forceinline__ void layer_mfma(
    const int tid, const int lane, const int wid, const int s0base,
    uint* lds, const float* __restrict__ Wf, const uint* __restrict__ Fr,
    const float* __restrict__ Bb,
    const uv4 (&xf)[2][2], uv4 (&sf0)[2], uv4 (&sf1)[2], uv4 (&sf2)[2], uv4 (&sf3)[2],
    uint (&sv)[8], float& tla0, float& tla1, float& tla2, float& tla3)
{
  constexpr int RB = L * (L + 1) / 2;
  float*  ldsF = (float*)lds;
  ushort* ldsH = (ushort*)lds;
  const int li = lane & 15, q4 = (lane >> 4) & 3;

  float cy[2], bb2[2], cu[2], tvs[2];
  #pragma unroll
  for (int nt = 0; nt < 2; ++nt) {
    const int nn = nt*16 + li;
    cy[nt]  = Wf[OFF_CY + L*32 + nn];
    bb2[nt] = Bb[L*32 + nn];
    cu[nt]  = Wf[OFF_CU + L*32 + nn];
    tvs[nt] = Wf[OFF_TV + (RB + L)*32 + nn];
  }
  float invv[2][4];
  #pragma unroll
  for (int m = 0; m < 2; ++m)
    #pragma unroll
    for (int r = 0; r < 4; ++r) {
      const int tk = wid*32 + m*16 + q4*4 + r;
      invv[m][r] = 1.0f / (sqrtf(fmaxf(ldsF[LNQ + tk], 0.f)) * 0.0625f + 1e-8f);
    }

  // ---- Y phase + D write into SLOT ----
  #pragma unroll
  for (int nt = 0; nt < 2; ++nt) {
    const uv4 by0 = ldB(Fr, 8 + L*4 + 0*2 + nt, lane);
    const uv4 by1 = ldB(Fr, 8 + L*4 + 1*2 + nt, lane);
    uv4 bp0, bp1, bp2;
    constexpr int PB = (L == 1) ? 0 : (L == 2) ? 1 : 3;
    if constexpr (L > 0) bp0 = ldB(Fr, 40 + (PB + 0)*2 + nt, lane);
    if constexpr (L > 1) bp1 = ldB(Fr, 40 + (PB + 1)*2 + nt, lane);
    if constexpr (L > 2) bp2 = ldB(Fr, 40 + (PB + 2)*2 + nt, lane);
    #pragma unroll
    for (int m = 0; m < 2; ++m) {
      f32x4 c = {cy[nt], cy[nt], cy[nt], cy[nt]};
      c = MF(xf[m][0], by0, c);
      c = MF(xf[m][1], by1, c);
      if constexpr (L > 0) c = MF(sf0[m], bp0, c);
      if constexpr (L > 1) c = MF(sf1[m], bp1, c);
      if constexpr (L > 2) c = MF(sf2[m], bp2, c);
      #pragma unroll
      for (int r = 0; r < 4; ++r) {
        const int tk = wid*32 + m*16 + q4*4 + r;
        const bool valid = (s0base > 0) || (tk >= NWARM);
        const float v = valid ? fmaf(invv[m][r], c[r], bb2[nt]) : 0.f;
        ldsH[tk*34 + nt*16 + li] = f2h(v);
      }
    }
  }
  __syncthreads();   // B1: D visible

  // ---- in-place scan (8 groups x 16 tokens) ----
  const int n = tid & 31, g = tid >> 5;
  const float a = Wf[OFF_AV + L*32 + n];
  float dv[HIST + 16];
  #pragma unroll
  for (int k = 0; k < HIST + 16; ++k) {
    const int p = g*16 - HIST + k;
    dv[k] = (p >= 0) ? h2f(ldsH[p*34 + n]) : 0.f;
  }
  __syncthreads();   // B2: D reads done before overwrite
  {
    float carry = 0.f;
    #pragma unroll
    for (int k = 0; k < HIST + 16; ++k) {
      carry = fmaf(a, carry, dv[k]);
      if (k >= HIST) ldsH[(g*16 + k - HIST)*34 + n] = f2h(carry);
    }
  }
  __syncthreads();   // B2b: s visible (needed by tl row reads)

  // ---- tl write + forward TV accumulation into future layers ----
  if (tid < PIPE) {
    float tlv;
    if constexpr (L == 0) tlv = tla0; else if constexpr (L == 1) tlv = tla1;
    else if constexpr (L == 2) tlv = tla2; else tlv = tla3;
    ldsF[LTL + tid] = Wf[OFF_CT + L] + tlv;
    const uint* sr = lds + tid*17;
    if constexpr (L == 0) {
      float t1 = 0.f, t2 = 0.f, t3 = 0.f;
      #pragma unroll
      for (int m2 = 0; m2 < 16; ++m2) {
        t1 = fdot2h(Fr[TVOFF + 1*16 + m2], sr[m2], t1);
        t2 = fdot2h(Fr[TVOFF + 3*16 + m2], sr[m2], t2);
        t3 = fdot2h(Fr[TVOFF + 6*16 + m2], sr[m2], t3);
      }
      tla1 += t1; tla2 += t2; tla3 += t3;
    } else if constexpr (L == 1) {
      float t2 = 0.f, t3 = 0.f;
      #pragma unroll
      for (int m2 = 0; m2 < 16; ++m2) {
        t2 = fdot2h(Fr[TVOFF + 4*16 + m2], sr[m2], t2);
        t3 = fdot2h(Fr[TVOFF + 7*16 + m2], sr[m2], t3);
      }
      tla2 += t2; tla3 += t3;
    } else if constexpr (L == 2) {
      float t3 = 0.f;
      #pragma unroll
      for (int m2 = 0; m2 < 16; ++m2)
        t3 = fdot2h(Fr[TVOFF + 8*16 + m2], sr[m2], t3);
      tla3 += t3;
    }
  }
  __syncthreads();   // B3: tl visible

  // ---- A-frags of s_L ----
  uv4 sA[2];
  #pragma unroll
  for (int m = 0; m < 2; ++m) {
    const uint* p = lds + (wid*32 + m*16 + li)*17 + q4*4;
    uv4 v; v[0] = p[0]; v[1] = p[1]; v[2] = p[2]; v[3] = p[3];
    sA[m] = v;
  }
  if constexpr (L == 0)      { sf0[0] = sA[0]; sf0[1] = sA[1]; }
  else if constexpr (L == 1) { sf1[0] = sA[0]; sf1[1] = sA[1]; }
  else if constexpr (L == 2) { sf2[0] = sA[0]; sf2[1] = sA[1]; }
  else                       { sf3[0] = sA[0]; sf3[1] = sA[1]; }

  // ---- U/ACC phase + w row-dot; save C-layout s into regs ----
  float wv[2][4] = {{0,0,0,0},{0,0,0,0}};
  float svf[2][2][4];
  #pragma unroll
  for (int nt = 0; nt < 2; ++nt) {
    const uv4 bu0 = ldB(Fr, 24 + L*4 + 0*2 + nt, lane);
    const uv4 bu1 = ldB(Fr, 24 + L*4 + 1*2 + nt, lane);
    uv4 br0, br1, br2;
    if constexpr (L > 0) br0 = ldB(Fr, 52 + (RB + 0)*2 + nt, lane);
    if constexpr (L > 1) br1 = ldB(Fr, 52 + (RB + 1)*2 + nt, lane);
    if constexpr (L > 2) br2 = ldB(Fr, 52 + (RB + 2)*2 + nt, lane);
    const uv4 brS = ldB(Fr, 52 + (RB + L)*2 + nt, lane);   // 0.5*R_self
    #pragma unroll
    for (int m = 0; m < 2; ++m) {
      f32x4 c = {0.f, 0.f, 0.f, 0.f};
      c = MF(xf[m][0], bu0, c);
      c = MF(xf[m][1], bu1, c);
      if constexpr (L > 0) c = MF(sf0[m], br0, c);
      if constexpr (L > 1) c = MF(sf1[m], br1, c);
      if constexpr (L > 2) c = MF(sf2[m], br2, c);
      c = MF(sA[m], brS, c);
      #pragma unroll
      for (int r = 0; r < 4; ++r) {
        const int tk = wid*32 + m*16 + q4*4 + r;
        const float sval = h2f(ldsH[tk*34 + nt*16 + li]);
        svf[m][nt][r] = sval;
        wv[m][r] = fmaf(c[r] + cu[nt] + tvs[nt], sval, wv[m][r]);
      }
    }
  }
  #pragma unroll
  for (int m = 0; m < 2; ++m)
    #pragma unroll
    for (int nt = 0; nt < 2; ++nt) {
      sv[(m*2 + nt)*2 + 0] = pack2(svf[m][nt][0], svf[m][nt][1]);
      sv[(m*2 + nt)*2 + 1] = pack2(svf[m][nt][2], svf[m][nt][3]);
    }
  #pragma unroll
  for (int m = 0; m < 2; ++m)
    #pragma unroll
    for (int r = 0; r < 4; ++r) {
      float v = wv[m][r];
      v += __shfl_xor(v, 1, 64); v += __shfl_xor(v, 2, 64);
      v += __shfl_xor(v, 4, 64); v += __shfl_xor(v, 8, 64);
      wv[m][r] = v;
    }
  if (li == 0) {
    #pragma unroll
    for (int m = 0; m < 2; ++m)
      #pragma unroll
      for (int r = 0; r < 4; ++r) {
        const int tk = wid*32 + m*16 + q4*4 + r;
        ldsF[LNQ + tk] += 2.f * (wv[m][r] + ldsF[LTL + tk]);
      }
  }
  __syncthreads();   // B4
}

// ---------------------------------------------------------------------------
// Main kernel (MFMA engine; slim LDS -> up to 4 blocks/CU at grid 1024).
// ---------------------------------------------------------------------------
__global__ __launch_bounds__(NTHR, 3) void ssm_main(
    const float* __restrict__ x, const float* __restrict__ Wf,
    const uint* __restrict__ Fr, const float* __restrict__ Bb,
    float* __restrict__ part)
{
  extern __shared__ uint lds[];
  float*  ldsF = (float*)lds;
  ushort* ldsH = (ushort*)lds;
  const int tid = threadIdx.x;
  const int lane = tid & 63, wid = tid >> 6;
  const int li = lane & 15, q4 = (lane >> 4) & 3;
  const int blk = blockIdx.x;
  const int bb = blk >> 7;                 // 128 blocks per sequence
  const int s0base = (blk & 127) * TOUT;

  // ---- stage x -> fp16 LDS rows [128][34] (overlays SLOT/SCR; init only) ----
  {
    const float4* xg4 = (const float4*)(x + (size_t)bb * S_ * DIN);
    #pragma unroll
    for (int k = 0; k < 8; ++k) {
      const int idx = k * NTHR + tid;
      const int tok = idx >> 4, c4 = idx & 15;
      const int lt = s0base - NWARM + tok;
      float4 v = make_float4(0.f, 0.f, 0.f, 0.f);
      if (lt >= 0) v = xg4[lt * 16 + c4];
      lds[tok*34 + 2*c4]     = pack2(v.x, v.y);
      lds[tok*34 + 2*c4 + 1] = pack2(v.z, v.w);
    }
  }
  __syncthreads();

  // ---- X A-frags (resident) ----
  uv4 xf[2][2];
  #pragma unroll
  for (int m = 0; m < 2; ++m)
    #pragma unroll
    for (int k = 0; k < 2; ++k) {
      const uint* p = lds + (wid*32 + m*16 + li)*34 + k*16 + q4*4;
      uv4 v; v[0] = p[0]; v[1] = p[1]; v[2] = p[2]; v[3] = p[3];
      xf[m][k] = v;
    }

  // ---- tlx precompute (token-threads): tla_l = TX_l . x ----
  float tla0 = 0.f, tla1 = 0.f, tla2 = 0.f, tla3 = 0.f;
  if (tid < PIPE) {
    const uint* xr = lds + tid*34;
    #pragma unroll 8
    for (int c2 = 0; c2 < 32; ++c2) {
      tla0 = fdot2h(Fr[TXOFF + 0*32 + c2], xr[c2], tla0);
      tla1 = fdot2h(Fr[TXOFF + 1*32 + c2], xr[c2], tla1);
      tla2 = fdot2h(Fr[TXOFF + 2*32 + c2], xr[c2], tla2);
      tla3 = fdot2h(Fr[TXOFF + 3*32 + c2], xr[c2], tla3);
    }
  }

  // ---- nq0 = g0 + 2 gx.x + x^T G x ----
  {
    float val[2][4] = {{0,0,0,0},{0,0,0,0}};
    #pragma unroll
    for (int nt = 0; nt < 4; ++nt) {
      const float gxv = 2.f * Wf[OFF_GX + nt*16 + li];
      const uv4 bg0 = ldB(Fr, 0*4 + nt, lane);
      const uv4 bg1 = ldB(Fr, 1*4 + nt, lane);
      #pragma unroll
      for (int m = 0; m < 2; ++m) {
        f32x4 c = {gxv, gxv, gxv, gxv};
        c = MF(xf[m][0], bg0, c);
        c = MF(xf[m][1], bg1, c);
        #pragma unroll
        for (int r = 0; r < 4; ++r) {
          const int tk = wid*32 + m*16 + q4*4 + r;
          const float xv = h2f(ldsH[tk*68 + nt*16 + li]);
          val[m][r] = fmaf(c[r], xv, val[m][r]);
        }
      }
    }
    const float g0 = Wf[OFF_G0];
    #pragma unroll
    for (int m = 0; m < 2; ++m)
      #pragma unroll
      for (int r = 0; r < 4; ++r) {
        float v = val[m][r];
        v += __shfl_xor(v, 1, 64); v += __shfl_xor(v, 2, 64);
        v += __shfl_xor(v, 4, 64); v += __shfl_xor(v, 8, 64);
        if (li == 0) ldsF[LNQ + wid*32 + m*16 + q4*4 + r] = g0 + v;
      }
  }
  __syncthreads();   // x region dead from here (xf/tla/nq0 captured)

  // ---- layers ----
  uv4 sf0[2], sf1[2], sf2[2], sf3[2];
  uint sv0[8], sv1[8], sv2[8], sv3[8];
  layer_mfma<0>(tid, lane, wid, s0base, lds, Wf, Fr, Bb, xf, sf0, sf1, sf2, sf3, sv0, tla0, tla1, tla2, tla3);
  layer_mfma<1>(tid, lane, wid, s0base, lds, Wf, Fr, Bb, xf, sf0, sf1, sf2, sf3, sv1, tla0, tla1, tla2, tla3);
  layer_mfma<2>(tid, lane, wid, s0base, lds, Wf, Fr, Bb, xf, sf0, sf1, sf2, sf3, sv2, tla0, tla1, tla2, tla3);
  layer_mfma<3>(tid, lane, wid, s0base, lds, Wf, Fr, Bb, xf, sf0, sf1, sf2, sf3, sv3, tla0, tla1, tla2, tla3);

  // ---- E1: per-token r; Sum r via wave-1 butterfly ----
  if (tid < PIPE) {
    const float rr = 1.0f / (sqrtf(fmaxf(ldsF[LNQ + tid], 0.f)) * 0.0625f + 1e-8f);
    ldsF[LTL + tid] = rr;
    if (tid >= NWARM) {
      float sm = rr;
      #pragma unroll
      for (int off = 1; off < 64; off <<= 1) sm += __shfl_xor(sm, off, 64);
      if (tid == NWARM) part[blk*193] = sm;
    }
  }
  __syncthreads();

  // ---- E2: register reduce (s sums + x sums) ----
  {
    float rrv[2][4], rr2[2];
    #pragma unroll
    for (int m = 0; m < 2; ++m) {
      #pragma unroll
      for (int r = 0; r < 4; ++r)
        rrv[m][r] = ldsF[LTL + wid*32 + m*16 + q4*4 + r];
      rr2[m] = ldsF[LTL + wid*32 + m*16 + li];
    }
#define SSUM(SVARR, LIDX)                                                     \
    {                                                                         \
      _Pragma("unroll")                                                       \
      for (int nt = 0; nt < 2; ++nt) {                                        \
        float a_ = 0.f;                                                       \
        _Pragma("unroll")                                                     \
        for (int m = 0; m < 2; ++m) {                                         \
          float v0_, v1_;                                                     \
          unpack2(SVARR[(m*2 + nt)*2 + 0], v0_, v1_);                         \
          a_ = fmaf(v0_, rrv[m][0], a_); a_ = fmaf(v1_, rrv[m][1], a_);       \
          unpack2(SVARR[(m*2 + nt)*2 + 1], v0_, v1_);                         \
          a_ = fmaf(v0_, rrv[m][2], a_); a_ = fmaf(v1_, rrv[m][3], a_);       \
        }                                                                     \
        a_ += __shfl_xor(a_, 16, 64); a_ += __shfl_xor(a_, 32, 64);           \
        if (lane < 16 && wid >= 2)                                            \
          ldsF[SCR_S + (((LIDX)*2 + nt)*2 + (wid - 2))*16 + li] = a_;         \
      }                                                                       \
    }
    SSUM(sv0, 0) SSUM(sv1, 1) SSUM(sv2, 2) SSUM(sv3, 3)
#undef SSUM
    // x sums from fp16 A-frags
    float ax[16];
    #pragma unroll
    for (int i = 0; i < 16; ++i) ax[i] = 0.f;
    #pragma unroll
    for (int m = 0; m < 2; ++m)
      #pragma unroll
      for (int kk = 0; kk < 2; ++kk)
        #pragma unroll
        for (int c = 0; c < 4; ++c) {
          float v0, v1; unpack2(xf[m][kk][c], v0, v1);
          ax[kk*8 + 2*c]     = fmaf(v0, rr2[m], ax[kk*8 + 2*c]);
          ax[kk*8 + 2*c + 1] = fmaf(v1, rr2[m], ax[kk*8 + 2*c + 1]);
        }
    #pragma unroll
    for (int i = 0; i < 16; ++i) {
      ax[i] += __shfl_xor(ax[i], 1, 64); ax[i] += __shfl_xor(ax[i], 2, 64);
      ax[i] += __shfl_xor(ax[i], 4, 64); ax[i] += __shfl_xor(ax[i], 8, 64);
    }
    if (li == 0 && wid >= 2) {
      #pragma unroll
      for (int kk = 0; kk < 2; ++kk)
        #pragma unroll
        for (int c = 0; c < 4; ++c) {
          const int col = kk*32 + q4*8 + 2*c;
          ldsF[SCR_X + (wid - 2)*64 + col]     = ax[kk*8 + 2*c];
          ldsF[SCR_X + (wid - 2)*64 + col + 1] = ax[kk*8 + 2*c + 1];
        }
    }
  }
  __syncthreads();

  // ---- E3: write part columns ----
  if (tid < 128) {
    const int l = tid >> 5, nt = (tid >> 4) & 1, l2 = tid & 15;
    part[blk*193 + 65 + l*32 + (tid & 31)] =
        ldsF[SCR_S + ((l*2 + nt)*2 + 0)*16 + l2] +
        ldsF[SCR_S + ((l*2 + nt)*2 + 1)*16 + l2];
  } else if (tid < 192) {
    const int c = tid - 128;
    part[blk*193 + 1 + c] = ldsF[SCR_X + c] + ldsF[SCR_X + 64 + c];
  }
}

// ---------------------------------------------------------------------------
// Final: reduce partials (128 rows/batch, 4-way ILP), mean, classifier MLP.
// ---------------------------------------------------------------------------
__global__ __launch_bounds__(256) void ssm_final(
    const float* __restrict__ part,
    const float* __restrict__ in_w, const float* __restrict__ in_b,
    const float* __restrict__ Cw, const float* __restrict__ Cb,
    const float* __restrict__ fsc,
    const float* __restrict__ w1, const float* __restrict__ b1,
    const float* __restrict__ w2, const float* __restrict__ b2,
    float* __restrict__ out)
{
  const int b = blockIdx.x, t = threadIdx.x;
  __shared__ float red[193];
  __shared__ float meanv[DM];
  __shared__ float h1[DM];
  if (t < 193) {
    float a0 = 0.f, a1 = 0.f, a2 = 0.f, a3 = 0.f;
    const float* pp = part + (size_t)b * 128 * 193 + t;
    for (int k = 0; k < 128; k += 4) {
      a0 += pp[(k + 0) * 193]; a1 += pp[(k + 1) * 193];
      a2 += pp[(k + 2) * 193]; a3 += pp[(k + 3) * 193];
    }
    red[t] = (a0 + a1) + (a2 + a3);
  }
  __syncthreads();
  {
    const float rho = red[0];
    float m = in_b[t] * rho;
    #pragma unroll 4
    for (int i = 0; i < 64; ++i) m = fmaf(in_w[t*64 + i], red[1 + i], m);
    for (int l = 0; l < NL; ++l) {
      #pragma unroll 4
      for (int n = 0; n < 32; ++n)
        m = fmaf(Cw[(l*DM + t)*NS + n], red[65 + l*32 + n], m);
      m = fmaf(Cb[l*DM + t], rho, m);
    }
    meanv[t] = fsc[t] * m * (1.0f / (float)S_);
  }
  __syncthreads();
  {
    float z = b1[t];
    for (int e = 0; e < DM; ++e) z = fmaf(w1[t*DM + e], meanv[e], z);
    h1[t] = z / (1.0f + expf(-z));
  }
  __syncthreads();
  if (t < 10) {
    float lg = b2[t];
    for (int e = 0; e < DM; ++e) lg = fmaf(w2[t*DM + e], h1[e], lg);
    out[b*10 + t] = lg;
  }
}

// ---------------------------------------------------------------------------
extern "C" void kernel_launch(void* const* d_in, const int* in_sizes, int n_in,
                              void* d_out, int out_size, void* d_ws, size_t ws_size,
                              hipStream_t stream)
{
  const float* x    = (const float*)d_in[0];
  const float* in_w = (const float*)d_in[1];
  const float* in_b = (const float*)d_in[2];
  const float* logA = (const float*)d_in[3];
  const float* Bw   = (const float*)d_in[4];
  const float* Bb   = (const float*)d_in[5];
  const float* Cw   = (const float*)d_in[6];
  const float* Cb   = (const float*)d_in[7];
  const float* nsc  = (const float*)d_in[8];
  const float* fsc  = (const float*)d_in[9];
  const float* w1   = (const float*)d_in[10];
  const float* b1   = (const float*)d_in[11];
  const float* w2   = (const float*)d_in[12];
  const float* b2   = (const float*)d_in[13];
  float* out  = (float*)d_out;
  float* wsf  = (float*)d_ws;
  uint*  Fr   = (uint*)(wsf + WS_FRAG);
  float* part = wsf + WS_PART;
  (void)in_sizes; (void)n_in; (void)out_size; (void)ws_size;

  ssm_prep<<<(PRE_N * 8 + 255) / 256, 256, 0, stream>>>(in_w, in_b, logA, Bw, Cw, Cb,
                                                        nsc, wsf, (ushort*)Fr);
  ssm_main<<<NBLK, NTHR, LDSN * sizeof(uint), stream>>>(x, wsf, Fr, Bb, part);
  ssm_final<<<B_, 256, 0, stream>>>(part, in_w, in_b, Cw, Cb, fsc, w1, b1, w2, b2, out);
}

// Round 15
// 101.487 us; speedup vs baseline: 1.0607x; 1.0607x over previous
//
#include <hip/hip_runtime.h>
#include <hip/hip_fp16.h>
#include <math.h>

#define B_    8
#define S_    8192
#define DIN   64
#define DM    256
#define NS    32
#define NL    4
#define TOUT  128
#define NWARM 64
#define PIPE  192            // 64 warm + 128 out
#define HIST  16             // scan window; a^17 ~ 7e-9
#define NBLK  512            // B_*S_/TOUT -> exactly 2 blocks/CU, zero tail
#define NTHR  256            // 4 waves; 3 Mtiles (48 tokens) per wave

// ---- fp32 precomputed-weight offsets (Wf) ----
#define OFF_G   0
#define OFF_GX  4096
#define OFF_G0  4160
#define OFF_WY  4224
#define OFF_WU  12416
#define OFF_P   20608
#define OFF_R   26752
#define OFF_CY  36992
#define OFF_CU  37120
#define OFF_TX  37248
#define OFF_TV  37504
#define OFF_CT  37824
#define OFF_CC  37828
#define OFF_AV  37832
#define PRE_N   37960

// ---- frag buffer (u32 units). 72 frag-units of 256 u32 + TX/TV tails ----
#define TXOFF  18432         // 4*32 u32
#define TVOFF  18560         // 10*16 u32
#define WS_FRAG 40960        // float offset of Fr in ws
#define WS_PART 65536        // float offset of part[512][193]

// ---- LDS u32 layout: x[192][34] | slots[4][192][17] | nq | tl ----
#define LX    0
#define LS0   6528           // slot L: LS0 + L*3264
#define LNQ   19584          // float[192]
#define LTL   19776          // float[192]
#define LDSN  19968          // 79,872 B -> 2 blocks/CU

typedef _Float16 h2_t  __attribute__((ext_vector_type(2)));
typedef _Float16 f16x8 __attribute__((ext_vector_type(8)));
typedef float    f32x4 __attribute__((ext_vector_type(4)));
typedef uint     uv4   __attribute__((ext_vector_type(4)));

__device__ __forceinline__ float h2f(ushort u) { return __half2float(__ushort_as_half(u)); }
__device__ __forceinline__ ushort f2h(float f) { return __half_as_ushort(__float2half(f)); }
__device__ __forceinline__ uint pack2(float a, float b) {
  return (uint)f2h(a) | ((uint)f2h(b) << 16);
}
__device__ __forceinline__ float fdot2h(uint w, uint v, float c) {
  return __builtin_amdgcn_fdot2(__builtin_bit_cast(h2_t, w),
                                __builtin_bit_cast(h2_t, v), c, false);
}
__device__ __forceinline__ f32x4 MF(uv4 a, uv4 b, f32x4 c) {
  return __builtin_amdgcn_mfma_f32_16x16x32_f16(
      __builtin_bit_cast(f16x8, a), __builtin_bit_cast(f16x8, b), c, 0, 0, 0);
}
__device__ __forceinline__ uv4 ldB(const uint* __restrict__ Fr, int unit, int lane) {
  return ((const uv4*)Fr)[unit * 64 + lane];
}

// ---------------------------------------------------------------------------
// Prep: fused fp32 matrices + direct fp16 fragment packing.
// 16 lanes per output (16 d-iters each) + shfl reduce over 16 lanes.
// ---------------------------------------------------------------------------
__global__ void ssm_prep(const float* __restrict__ in_w, const float* __restrict__ in_b,
                         const float* __restrict__ logA,
                         const float* __restrict__ Bw, const float* __restrict__ Cw,
                         const float* __restrict__ Cb, const float* __restrict__ nsc,
                         float* __restrict__ Wf, ushort* __restrict__ FrH)
{
  const int gid = blockIdx.x * 256 + threadIdx.x;
  const int t = gid >> 4, piece = gid & 15;
  if (t >= PRE_N) return;
  const int d0 = piece * 16, d1 = d0 + 16;
  const int pm6[6]  = {1,2,2,3,3,3}, pl6[6] = {0,0,1,0,1,2};
  const int rm10[10] = {0,1,1,2,2,2,3,3,3,3}, rl10[10] = {0,0,1,0,1,2,0,1,2,3};
  float s = 0.f;
  if (t < OFF_GX) {
    const int i = t >> 6, jj = t & 63;
    for (int d = d0; d < d1; ++d) s = fmaf(in_w[d*64 + i], in_w[d*64 + jj], s);
  } else if (t < OFF_G0) {
    const int i = t - OFF_GX;
    for (int d = d0; d < d1; ++d) s = fmaf(in_w[d*64 + i], in_b[d], s);
  } else if (t < OFF_WY) {
    if (t == OFF_G0) { for (int d = d0; d < d1; ++d) s = fmaf(in_b[d], in_b[d], s); }
  } else if (t < OFF_WU) {
    const int r = t - OFF_WY, l = r >> 11, qq = r & 2047, c = qq >> 5, n = qq & 31;
    for (int d = d0; d < d1; ++d)
      s = fmaf(Bw[(l*NS + n)*DM + d] * nsc[l*DM + d], in_w[d*64 + c], s);
  } else if (t < OFF_P) {
    const int r = t - OFF_WU, l = r >> 11, qq = r & 2047, c = qq >> 5, n = qq & 31;
    for (int d = d0; d < d1; ++d)
      s = fmaf(Cw[(l*DM + d)*NS + n], in_w[d*64 + c], s);
  } else if (t < OFF_R) {
    const int r = t - OFF_P, pi = r >> 10, qq = r & 1023, np = qq >> 5, n = qq & 31;
    const int m = pm6[pi], lp = pl6[pi];
    for (int d = d0; d < d1; ++d)
      s = fmaf(Bw[(m*NS + n)*DM + d] * nsc[m*DM + d], Cw[(lp*DM + d)*NS + np], s);
  } else if (t < OFF_CY) {
    const int r = t - OFF_R, ri = r >> 10, qq = r & 1023, np = qq >> 5, n = qq & 31;
    const int m = rm10[ri], lp = rl10[ri];
    for (int d = d0; d < d1; ++d)
      s = fmaf(Cw[(m*DM + d)*NS + n], Cw[(lp*DM + d)*NS + np], s);
  } else if (t < OFF_CU) {
    const int r = t - OFF_CY, l = r >> 5, n = r & 31;
    for (int d = d0; d < d1; ++d) {
      float bs = in_b[d];
      for (int lp = 0; lp < l; ++lp) bs += Cb[lp*DM + d];
      s = fmaf(Bw[(l*NS + n)*DM + d] * nsc[l*DM + d], bs, s);
    }
  } else if (t < OFF_TX) {
    const int r = t - OFF_CU, l = r >> 5, n = r & 31;
    for (int d = d0; d < d1; ++d) {
      float bs = in_b[d];
      for (int lp = 0; lp < l; ++lp) bs += Cb[lp*DM + d];
      s = fmaf(Cw[(l*DM + d)*NS + n], bs, s);
    }
  } else if (t < OFF_TV) {
    const int r = t - OFF_TX, l = r >> 6, i = r & 63;
    for (int d = d0; d < d1; ++d) s = fmaf(Cb[l*DM + d], in_w[d*64 + i], s);
  } else if (t < OFF_CT) {
    const int r = t - OFF_TV, vi = r >> 5, np = r & 31;
    const int m = rm10[vi], lp = rl10[vi];
    for (int d = d0; d < d1; ++d)
      s = fmaf(Cb[m*DM + d], Cw[(lp*DM + d)*NS + np], s);
  } else if (t < OFF_CC) {
    const int l = t - OFF_CT;
    for (int d = d0; d < d1; ++d) {
      float bs = in_b[d];
      for (int lp = 0; lp < l; ++lp) bs += Cb[lp*DM + d];
      s = fmaf(Cb[l*DM + d], bs, s);
    }
  } else if (t < OFF_AV) {
    const int l = t - OFF_CC;
    for (int d = d0; d < d1; ++d) s = fmaf(Cb[l*DM + d], Cb[l*DM + d], s);
  } else {
    s = (piece == 0) ? 1.0f / (1.0f + expf(-logA[t - OFF_AV])) : 0.f;
  }
  s += __shfl_xor(s, 1, 64);
  s += __shfl_xor(s, 2, 64);
  s += __shfl_xor(s, 4, 64);
  s += __shfl_xor(s, 8, 64);
  if (piece != 0) return;
  Wf[t] = s;

  // ---- direct fragment packing (inverse of the frag-unit mapping) ----
  if (t < OFF_GX) {                      // G [64][64]
    const int kk = t >> 6, n = t & 63;
    const int u = (kk >> 5)*4 + (n >> 4);
    const int lane = (((kk & 31) >> 3) << 4) + (n & 15);
    FrH[(u*256 + lane*4 + ((kk & 7) >> 1))*2 + (kk & 1)] = f2h(s);
  } else if (t >= OFF_WY && t < OFF_WU) {   // WY [4][64][32]
    const int r = t - OFF_WY, l = r >> 11, kk = (r & 2047) >> 5, n = r & 31;
    const int u = 8 + l*4 + (kk >> 5)*2 + (n >> 4);
    const int lane = (((kk & 31) >> 3) << 4) + (n & 15);
    FrH[(u*256 + lane*4 + ((kk & 7) >> 1))*2 + (kk & 1)] = f2h(s);
  } else if (t >= OFF_WU && t < OFF_P) {    // WU [4][64][32]
    const int r = t - OFF_WU, l = r >> 11, kk = (r & 2047) >> 5, n = r & 31;
    const int u = 24 + l*4 + (kk >> 5)*2 + (n >> 4);
    const int lane = (((kk & 31) >> 3) << 4) + (n & 15);
    FrH[(u*256 + lane*4 + ((kk & 7) >> 1))*2 + (kk & 1)] = f2h(s);
  } else if (t >= OFF_P && t < OFF_R) {     // P [6][32][32]
    const int r = t - OFF_P, pi = r >> 10, kk = (r & 1023) >> 5, n = r & 31;
    const int u = 40 + pi*2 + (n >> 4);
    const int lane = ((kk >> 3) << 4) + (n & 15);
    FrH[(u*256 + lane*4 + ((kk & 7) >> 1))*2 + (kk & 1)] = f2h(s);
  } else if (t >= OFF_R && t < OFF_CY) {    // R [10][32][32], self x0.5
    const int r = t - OFF_R, ri = r >> 10, kk = (r & 1023) >> 5, n = r & 31;
    const int u = 52 + ri*2 + (n >> 4);
    const int lane = ((kk >> 3) << 4) + (n & 15);
    const float sc = (ri == 0 || ri == 2 || ri == 5 || ri == 9) ? 0.5f : 1.f;
    FrH[(u*256 + lane*4 + ((kk & 7) >> 1))*2 + (kk & 1)] = f2h(s * sc);
  } else if (t >= OFF_TX && t < OFF_TV) {   // TX packed pairs
    const int r = t - OFF_TX, l = r >> 6, i = r & 63;
    FrH[(TXOFF + l*32 + (i >> 1))*2 + (i & 1)] = f2h(s);
  } else if (t >= OFF_TV && t < OFF_CT) {   // TV packed pairs
    const int r = t - OFF_TV, vi = r >> 5, nn = r & 31;
    FrH[(TVOFF + vi*16 + (nn >> 1))*2 + (nn & 1)] = f2h(s);
  }
}

// ---------------------------------------------------------------------------
// Per-layer body: Y MFMA -> D write (slot L) -> in-place scan -> U MFMA -> nq.
// 3 Mtiles per wave (rows wid*48 .. wid*48+47).
// ---------------------------------------------------------------------------
template<int L>
__device__ __forceinline__ void layer_mfma(
    const int tid, const int lane, const int wid, const int s0base,
    uint* lds, const float* __restrict__ Wf, const uint* __restrict__ Fr,
    const float* __restrict__ Bb,
    const uv4 (&xf)[3][2], uv4 (&sf0)[3], uv4 (&sf1)[3], uv4 (&sf2)[3], uv4 (&sf3)[3])
{
  constexpr int RB = L * (L + 1) / 2;
  constexpr int PB = (L == 1) ? 0 : (L == 2) ? 1 : 3;
  constexpr int SL = LS0 + L * 3264;
  float*  ldsF = (float*)lds;
  ushort* ldsH = (ushort*)lds;
  const int li = lane & 15, q4 = (lane >> 4) & 3;

  float cy[2], bb2[2], cu[2], tvs[2];
  #pragma unroll
  for (int nt = 0; nt < 2; ++nt) {
    const int nn = nt*16 + li;
    cy[nt]  = Wf[OFF_CY + L*32 + nn];
    bb2[nt] = Bb[L*32 + nn];
    cu[nt]  = Wf[OFF_CU + L*32 + nn];
    tvs[nt] = Wf[OFF_TV + (RB + L)*32 + nn];
  }
  float invv[3][4];
  #pragma unroll
  for (int m = 0; m < 3; ++m)
    #pragma unroll
    for (int r = 0; r < 4; ++r) {
      const int tk = wid*48 + m*16 + q4*4 + r;
      invv[m][r] = 1.0f / (sqrtf(fmaxf(ldsF[LNQ + tk], 0.f)) * 0.0625f + 1e-8f);
    }

  // ---- Y phase + D write (into slot L) ----
  #pragma unroll
  for (int nt = 0; nt < 2; ++nt) {
    const uv4 by0 = ldB(Fr, 8 + L*4 + 0*2 + nt, lane);
    const uv4 by1 = ldB(Fr, 8 + L*4 + 1*2 + nt, lane);
    uv4 bp0, bp1, bp2;
    if constexpr (L > 0) bp0 = ldB(Fr, 40 + (PB + 0)*2 + nt, lane);
    if constexpr (L > 1) bp1 = ldB(Fr, 40 + (PB + 1)*2 + nt, lane);
    if constexpr (L > 2) bp2 = ldB(Fr, 40 + (PB + 2)*2 + nt, lane);
    #pragma unroll
    for (int m = 0; m < 3; ++m) {
      f32x4 c = {cy[nt], cy[nt], cy[nt], cy[nt]};
      c = MF(xf[m][0], by0, c);
      c = MF(xf[m][1], by1, c);
      if constexpr (L > 0) c = MF(sf0[m], bp0, c);
      if constexpr (L > 1) c = MF(sf1[m], bp1, c);
      if constexpr (L > 2) c = MF(sf2[m], bp2, c);
      #pragma unroll
      for (int r = 0; r < 4; ++r) {
        const int tk = wid*48 + m*16 + q4*4 + r;
        const bool valid = (s0base > 0) || (tk >= NWARM);
        const float v = valid ? fmaf(invv[m][r], c[r], bb2[nt]) : 0.f;
        ldsH[SL*2 + tk*34 + nt*16 + li] = f2h(v);
      }
    }
  }
  __syncthreads();   // B1: D visible

  // ---- in-place scan: 8 groups of 24 tokens; stage-1 regs then Horner ----
  const int n = tid & 31, g = tid >> 5;
  const float a = Wf[OFF_AV + L*32 + n];
  float dv[HIST + 24];
  #pragma unroll
  for (int k = 0; k < HIST + 24; ++k) {
    const int p = g*24 - HIST + k;
    dv[k] = (p >= 0) ? h2f(ldsH[SL*2 + p*34 + n]) : 0.f;
  }
  __syncthreads();   // B2: all D reads complete before s overwrites

  {
    float carry = 0.f;
    #pragma unroll
    for (int k = 0; k < HIST + 24; ++k) {
      carry = fmaf(a, carry, dv[k]);
      if (k >= HIST) ldsH[SL*2 + (g*24 + k - HIST)*34 + n] = f2h(carry);
    }
  }
  // ---- tl per token (x + slots lp<L; none touches slot L) ----
  if (tid < PIPE) {
    float tl = Wf[OFF_CT + L];
    const uint* xr = lds + LX + tid*34;
    #pragma unroll 8
    for (int c2 = 0; c2 < 32; ++c2) tl = fdot2h(Fr[TXOFF + L*32 + c2], xr[c2], tl);
    if constexpr (L > 0) { const uint* sr = lds + LS0 + 0*3264 + tid*17;
      #pragma unroll
      for (int m2 = 0; m2 < 16; ++m2) tl = fdot2h(Fr[TVOFF + (RB+0)*16 + m2], sr[m2], tl); }
    if constexpr (L > 1) { const uint* sr = lds + LS0 + 1*3264 + tid*17;
      #pragma unroll
      for (int m2 = 0; m2 < 16; ++m2) tl = fdot2h(Fr[TVOFF + (RB+1)*16 + m2], sr[m2], tl); }
    if constexpr (L > 2) { const uint* sr = lds + LS0 + 2*3264 + tid*17;
      #pragma unroll
      for (int m2 = 0; m2 < 16; ++m2) tl = fdot2h(Fr[TVOFF + (RB+2)*16 + m2], sr[m2], tl); }
    ldsF[LTL + tid] = tl;
  }
  __syncthreads();   // B3: s + tl visible

  // ---- load S_L A-frags ----
  uv4 sA[3];
  #pragma unroll
  for (int m = 0; m < 3; ++m) {
    const uint* p = lds + SL + (wid*48 + m*16 + li)*17 + q4*4;
    uv4 v; v[0] = p[0]; v[1] = p[1]; v[2] = p[2]; v[3] = p[3];
    sA[m] = v;
  }
  if constexpr (L == 0)      { sf0[0] = sA[0]; sf0[1] = sA[1]; sf0[2] = sA[2]; }
  else if constexpr (L == 1) { sf1[0] = sA[0]; sf1[1] = sA[1]; sf1[2] = sA[2]; }
  else if constexpr (L == 2) { sf2[0] = sA[0]; sf2[1] = sA[1]; sf2[2] = sA[2]; }
  else                       { sf3[0] = sA[0]; sf3[1] = sA[1]; sf3[2] = sA[2]; }

  // ---- U/ACC phase + w row-dot ----
  float wv[3][4] = {{0,0,0,0},{0,0,0,0},{0,0,0,0}};
  #pragma unroll
  for (int nt = 0; nt < 2; ++nt) {
    const uv4 bu0 = ldB(Fr, 24 + L*4 + 0*2 + nt, lane);
    const uv4 bu1 = ldB(Fr, 24 + L*4 + 1*2 + nt, lane);
    uv4 br0, br1, br2;
    if constexpr (L > 0) br0 = ldB(Fr, 52 + (RB + 0)*2 + nt, lane);
    if constexpr (L > 1) br1 = ldB(Fr, 52 + (RB + 1)*2 + nt, lane);
    if constexpr (L > 2) br2 = ldB(Fr, 52 + (RB + 2)*2 + nt, lane);
    const uv4 brS = ldB(Fr, 52 + (RB + L)*2 + nt, lane);   // 0.5*R_self
    #pragma unroll
    for (int m = 0; m < 3; ++m) {
      f32x4 c = {0.f, 0.f, 0.f, 0.f};
      c = MF(xf[m][0], bu0, c);
      c = MF(xf[m][1], bu1, c);
      if constexpr (L > 0) c = MF(sf0[m], br0, c);
      if constexpr (L > 1) c = MF(sf1[m], br1, c);
      if constexpr (L > 2) c = MF(sf2[m], br2, c);
      c = MF(sA[m], brS, c);
      #pragma unroll
      for (int r = 0; r < 4; ++r) {
        const int tk = wid*48 + m*16 + q4*4 + r;
        const float sv = h2f(ldsH[SL*2 + tk*34 + nt*16 + li]);
        wv[m][r] = fmaf(c[r] + cu[nt] + tvs[nt], sv, wv[m][r]);
      }
    }
  }
  #pragma unroll
  for (int m = 0; m < 3; ++m)
    #pragma unroll
    for (int r = 0; r < 4; ++r) {
      float v = wv[m][r];
      v += __shfl_xor(v, 1, 64); v += __shfl_xor(v, 2, 64);
      v += __shfl_xor(v, 4, 64); v += __shfl_xor(v, 8, 64);
      wv[m][r] = v;
    }
  if (li == 0) {
    #pragma unroll
    for (int m = 0; m < 3; ++m)
      #pragma unroll
      for (int r = 0; r < 4; ++r) {
        const int tk = wid*48 + m*16 + q4*4 + r;
        ldsF[LNQ + tk] += 2.f * (wv[m][r] + ldsF[LTL + tk]);
      }
  }
  __syncthreads();   // B4: nq updated
}

// ---------------------------------------------------------------------------
// Main kernel (MFMA engine; grid 512 = exactly 2 blocks/CU).
// ---------------------------------------------------------------------------
__global__ __launch_bounds__(NTHR, 2) void ssm_main(
    const float* __restrict__ x, const float* __restrict__ Wf,
    const uint* __restrict__ Fr, const float* __restrict__ Bb,
    float* __restrict__ part)
{
  extern __shared__ uint lds[];
  float*  ldsF = (float*)lds;
  ushort* ldsH = (ushort*)lds;
  const int tid = threadIdx.x;
  const int lane = tid & 63, wid = tid >> 6;
  const int li = lane & 15, q4 = (lane >> 4) & 3;
  const int blk = blockIdx.x;
  const int bb = blk >> 6;                 // 64 chunks per sequence
  const int s0base = (blk & 63) * TOUT;

  // ---- stage x -> fp16 LDS rows [192][34] ----
  {
    const float4* xg4 = (const float4*)(x + (size_t)bb * S_ * DIN);
    #pragma unroll
    for (int k = 0; k < 12; ++k) {
      const int idx = k * NTHR + tid;
      const int tok = idx >> 4, c4 = idx & 15;
      const int lt = s0base - NWARM + tok;
      float4 v = make_float4(0.f, 0.f, 0.f, 0.f);
      if (lt >= 0) v = xg4[lt * 16 + c4];
      lds[LX + tok*34 + 2*c4]     = pack2(v.x, v.y);
      lds[LX + tok*34 + 2*c4 + 1] = pack2(v.z, v.w);
    }
  }
  __syncthreads();

  // ---- X A-frags (resident) ----
  uv4 xf[3][2];
  #pragma unroll
  for (int m = 0; m < 3; ++m)
    #pragma unroll
    for (int k = 0; k < 2; ++k) {
      const uint* p = lds + LX + (wid*48 + m*16 + li)*34 + k*16 + q4*4;
      uv4 v; v[0] = p[0]; v[1] = p[1]; v[2] = p[2]; v[3] = p[3];
      xf[m][k] = v;
    }

  // ---- nq0 = g0 + 2 gx.x + x^T G x ----
  {
    float val[3][4] = {{0,0,0,0},{0,0,0,0},{0,0,0,0}};
    #pragma unroll
    for (int nt = 0; nt < 4; ++nt) {
      const float gxv = 2.f * Wf[OFF_GX + nt*16 + li];
      const uv4 bg0 = ldB(Fr, 0*4 + nt, lane);
      const uv4 bg1 = ldB(Fr, 1*4 + nt, lane);
      #pragma unroll
      for (int m = 0; m < 3; ++m) {
        f32x4 c = {gxv, gxv, gxv, gxv};
        c = MF(xf[m][0], bg0, c);
        c = MF(xf[m][1], bg1, c);
        #pragma unroll
        for (int r = 0; r < 4; ++r) {
          const int tk = wid*48 + m*16 + q4*4 + r;
          const float xv = h2f(ldsH[tk*68 + nt*16 + li]);
          val[m][r] = fmaf(c[r], xv, val[m][r]);
        }
      }
    }
    const float g0 = Wf[OFF_G0];
    #pragma unroll
    for (int m = 0; m < 3; ++m)
      #pragma unroll
      for (int r = 0; r < 4; ++r) {
        float v = val[m][r];
        v += __shfl_xor(v, 1, 64); v += __shfl_xor(v, 2, 64);
        v += __shfl_xor(v, 4, 64); v += __shfl_xor(v, 8, 64);
        if (li == 0) ldsF[LNQ + wid*48 + m*16 + q4*4 + r] = g0 + v;
      }
  }
  __syncthreads();

  // ---- layers ----
  uv4 sf0[3], sf1[3], sf2[3], sf3[3];
  layer_mfma<0>(tid, lane, wid, s0base, lds, Wf, Fr, Bb, xf, sf0, sf1, sf2, sf3);
  layer_mfma<1>(tid, lane, wid, s0base, lds, Wf, Fr, Bb, xf, sf0, sf1, sf2, sf3);
  layer_mfma<2>(tid, lane, wid, s0base, lds, Wf, Fr, Bb, xf, sf0, sf1, sf2, sf3);
  layer_mfma<3>(tid, lane, wid, s0base, lds, Wf, Fr, Bb, xf, sf0, sf1, sf2, sf3);

  // ---- final r + block partial sums (6 narrow passes over dead x region) ----
  float rr = 0.f;
  if (tid >= NWARM && tid < PIPE)
    rr = 1.0f / (sqrtf(fmaxf(ldsF[LNQ + tid], 0.f)) * 0.0625f + 1e-8f);
  const int jj = tid - NWARM;             // 0..127 for output tokens
  float* pf = (float*)lds;                // overlays x (dead)

  // pass A1: [r | x0..31 * r]
  if (tid >= NWARM && tid < PIPE) {
    pf[jj*33] = rr;
    const float4* xr4 = (const float4*)(x + ((size_t)bb * S_ + (size_t)(s0base + jj)) * DIN);
    #pragma unroll
    for (int c4 = 0; c4 < 8; ++c4) {
      const float4 v = xr4[c4];
      pf[jj*33 + 1 + 4*c4] = v.x * rr; pf[jj*33 + 2 + 4*c4] = v.y * rr;
      pf[jj*33 + 3 + 4*c4] = v.z * rr; pf[jj*33 + 4 + 4*c4] = v.w * rr;
    }
  }
  __syncthreads();
  if (tid < 33) { float s = 0.f;
    for (int k = 0; k < TOUT; ++k) s += pf[k*33 + tid];
    part[blk*193 + tid] = s; }
  __syncthreads();
  // pass A2: x32..63 * r
  if (tid >= NWARM && tid < PIPE) {
    const float4* xr4 = (const float4*)(x + ((size_t)bb * S_ + (size_t)(s0base + jj)) * DIN);
    #pragma unroll
    for (int c4 = 8; c4 < 16; ++c4) {
      const float4 v = xr4[c4];
      const int o = 4*c4 - 32;
      pf[jj*33 + o]     = v.x * rr; pf[jj*33 + o + 1] = v.y * rr;
      pf[jj*33 + o + 2] = v.z * rr; pf[jj*33 + o + 3] = v.w * rr;
    }
  }
  __syncthreads();
  if (tid < 32) { float s = 0.f;
    for (int k = 0; k < TOUT; ++k) s += pf[k*33 + tid];
    part[blk*193 + 33 + tid] = s; }
  __syncthreads();
  // passes B..E: s_l * r
  for (int l = 0; l < 4; ++l) {
    if (tid >= NWARM && tid < PIPE) {
      #pragma unroll
      for (int m2 = 0; m2 < 16; ++m2) {
        const uint w = lds[LS0 + l*3264 + tid*17 + m2];
        pf[jj*33 + 2*m2]     = h2f((ushort)(w & 0xffffu)) * rr;
        pf[jj*33 + 2*m2 + 1] = h2f((ushort)(w >> 16)) * rr;
      }
    }
    __syncthreads();
    if (tid < 32) { float s = 0.f;
      for (int k = 0; k < TOUT; ++k) s += pf[k*33 + tid];
      part[blk*193 + 65 + l*32 + tid] = s; }
    __syncthreads();
  }
}

// ---------------------------------------------------------------------------
// Final: reduce partials (64 rows/batch, 4-way ILP), mean, classifier MLP.
// ---------------------------------------------------------------------------
__global__ __launch_bounds__(256) void ssm_final(
    const float* __restrict__ part,
    const float* __restrict__ in_w, const float* __restrict__ in_b,
    const float* __restrict__ Cw, const float* __restrict__ Cb,
    const float* __restrict__ fsc,
    const float* __restrict__ w1, const float* __restrict__ b1,
    const float* __restrict__ w2, const float* __restrict__ b2,
    float* __restrict__ out)
{
  const int b = blockIdx.x, t = threadIdx.x;
  __shared__ float red[193];
  __shared__ float meanv[DM];
  __shared__ float h1[DM];
  if (t < 193) {
    float a0 = 0.f, a1 = 0.f, a2 = 0.f, a3 = 0.f;
    const float* pp = part + (size_t)b * 64 * 193 + t;
    for (int k = 0; k < 64; k += 4) {
      a0 += pp[(k + 0) * 193]; a1 += pp[(k + 1) * 193];
      a2 += pp[(k + 2) * 193]; a3 += pp[(k + 3) * 193];
    }
    red[t] = (a0 + a1) + (a2 + a3);
  }
  __syncthreads();
  {
    const float rho = red[0];
    float m = in_b[t] * rho;
    #pragma unroll 4
    for (int i = 0; i < 64; ++i) m = fmaf(in_w[t*64 + i], red[1 + i], m);
    for (int l = 0; l < NL; ++l) {
      #pragma unroll 4
      for (int n = 0; n < 32; ++n)
        m = fmaf(Cw[(l*DM + t)*NS + n], red[65 + l*32 + n], m);
      m = fmaf(Cb[l*DM + t], rho, m);
    }
    meanv[t] = fsc[t] * m * (1.0f / (float)S_);
  }
  __syncthreads();
  {
    float z = b1[t];
    for (int e = 0; e < DM; ++e) z = fmaf(w1[t*DM + e], meanv[e], z);
    h1[t] = z / (1.0f + expf(-z));
  }
  __syncthreads();
  if (t < 10) {
    float lg = b2[t];
    for (int e = 0; e < DM; ++e) lg = fmaf(w2[t*DM + e], h1[e], lg);
    out[b*10 + t] = lg;
  }
}

// ---------------------------------------------------------------------------
extern "C" void kernel_launch(void* const* d_in, const int* in_sizes, int n_in,
                              void* d_out, int out_size, void* d_ws, size_t ws_size,
                              hipStream_t stream)
{
  const float* x    = (const float*)d_in[0];
  const float* in_w = (const float*)d_in[1];
  const float* in_b = (const float*)d_in[2];
  const float* logA = (const float*)d_in[3];
  const float* Bw   = (const float*)d_in[4];
  const float* Bb   = (const float*)d_in[5];
  const float* Cw   = (const float*)d_in[6];
  const float* Cb   = (const float*)d_in[7];
  const float* nsc  = (const float*)d_in[8];
  const float* fsc  = (const float*)d_in[9];
  const float* w1   = (const float*)d_in[10];
  const float* b1   = (const float*)d_in[11];
  const float* w2   = (const float*)d_in[12];
  const float* b2   = (const float*)d_in[13];
  float* out  = (float*)d_out;
  float* wsf  = (float*)d_ws;
  uint*  Fr   = (uint*)(wsf + WS_FRAG);
  float* part = wsf + WS_PART;
  (void)in_sizes; (void)n_in; (void)out_size; (void)ws_size;

  ssm_prep<<<(PRE_N * 16 + 255) / 256, 256, 0, stream>>>(in_w, in_b, logA, Bw, Cw, Cb,
                                                         nsc, wsf, (ushort*)Fr);
  ssm_main<<<NBLK, NTHR, LDSN * sizeof(uint), stream>>>(x, wsf, Fr, Bb, part);
  ssm_final<<<B_, 256, 0, stream>>>(part, in_w, in_b, Cw, Cb, fsc, w1, b1, w2, b2, out);
}

// Round 16
// 77.425 us; speedup vs baseline: 1.3903x; 1.3108x over previous
//
#include <hip/hip_runtime.h>
#include <hip/hip_fp16.h>
#include <math.h>

#define B_    8
#define S_    8192
#define DIN   64
#define DM    256
#define NS    32
#define NL    4
#define TOUT  128
#define NWARM 64
#define PIPE  192            // 64 warm + 128 out
#define HIST  16             // scan window; a^17 ~ 7e-9
#define NBLK  512            // B_*S_/TOUT -> exactly 2 blocks/CU, zero tail
#define NTHR  256            // 4 waves; 3 Mtiles (48 tokens) per wave

// ---- fp32 precomputed-weight offsets (Wf) ----
#define OFF_G   0
#define OFF_GX  4096
#define OFF_G0  4160
#define OFF_WY  4224
#define OFF_WU  12416
#define OFF_P   20608
#define OFF_R   26752
#define OFF_CY  36992
#define OFF_CU  37120
#define OFF_TX  37248
#define OFF_TV  37504
#define OFF_CT  37824
#define OFF_CC  37828
#define OFF_AV  37832
#define PRE_N   37960

// ---- frag buffer (u32 units). 72 frag-units of 256 u32 + TX/TV tails ----
#define TXOFF  18432         // 4*32 u32
#define TVOFF  18560         // 10*16 u32
#define WS_FRAG 40960        // float offset of Fr in ws
#define WS_PART 65536        // float offset of part[512][193]
#define WS_XP   165888       // float offset of transposed staging
//   in_wT [64][256] at +0, CwT [128][256] at +16384, bsT [4][256] at +49152

// ---- LDS u32 layout: x[192][34] | slots[4][192][17] | nq | tl ----
#define LX    0
#define LS0   6528           // slot L: LS0 + L*3264
#define LNQ   19584          // float[192]
#define LTL   19776          // float[192]
#define LDSN  19968          // 79,872 B -> 2 blocks/CU

typedef _Float16 h2_t  __attribute__((ext_vector_type(2)));
typedef _Float16 f16x8 __attribute__((ext_vector_type(8)));
typedef float    f32x4 __attribute__((ext_vector_type(4)));
typedef uint     uv4   __attribute__((ext_vector_type(4)));

__device__ __forceinline__ float h2f(ushort u) { return __half2float(__ushort_as_half(u)); }
__device__ __forceinline__ ushort f2h(float f) { return __half_as_ushort(__float2half(f)); }
__device__ __forceinline__ uint pack2(float a, float b) {
  return (uint)f2h(a) | ((uint)f2h(b) << 16);
}
__device__ __forceinline__ float fdot2h(uint w, uint v, float c) {
  return __builtin_amdgcn_fdot2(__builtin_bit_cast(h2_t, w),
                                __builtin_bit_cast(h2_t, v), c, false);
}
__device__ __forceinline__ f32x4 MF(uv4 a, uv4 b, f32x4 c) {
  return __builtin_amdgcn_mfma_f32_16x16x32_f16(
      __builtin_bit_cast(f16x8, a), __builtin_bit_cast(f16x8, b), c, 0, 0, 0);
}
__device__ __forceinline__ uv4 ldB(const uint* __restrict__ Fr, int unit, int lane) {
  return ((const uv4*)Fr)[unit * 64 + lane];
}

// ---------------------------------------------------------------------------
// Xpose: materialize contiguous-over-d rows for prep's column operands.
// in_wT[i][d] = in_w[d][i]; CwT[(l,n)][d] = Cw[l][d][n];
// bsT[l][d] = in_b[d] + sum_{lp<l} Cb[lp][d].
// ---------------------------------------------------------------------------
__global__ void ssm_xpose(const float* __restrict__ in_w, const float* __restrict__ Cw,
                          const float* __restrict__ in_b, const float* __restrict__ Cb,
                          float* __restrict__ xp)
{
  const int g = blockIdx.x * 256 + threadIdx.x;
  if (g < 64 * 256) {
    const int i = g >> 8, d = g & 255;
    xp[g] = in_w[d * 64 + i];
  } else if (g < 64 * 256 + 128 * 256) {
    const int r = g - 64 * 256, ln = r >> 8, d = r & 255;
    const int l = ln >> 5, n = ln & 31;
    xp[16384 + r] = Cw[(l * DM + d) * NS + n];
  } else if (g < 64 * 256 + 128 * 256 + 4 * 256) {
    const int r = g - (64 * 256 + 128 * 256), l = r >> 8, d = r & 255;
    float bs = in_b[d];
    for (int lp = 0; lp < l; ++lp) bs += Cb[lp * DM + d];
    xp[49152 + r] = bs;
  }
}

// ---------------------------------------------------------------------------
// Prep: wave-per-output; all operand reads contiguous over d (float4/lane).
// Lane-0 writes Wf + the fp16 fragment bytes (mapping identical to r11-15).
// ---------------------------------------------------------------------------
__global__ __launch_bounds__(256) void ssm_prep(
    const float* __restrict__ logA, const float* __restrict__ Bw,
    const float* __restrict__ nsc, const float* __restrict__ in_b,
    const float* __restrict__ Cb, const float* __restrict__ xp,
    float* __restrict__ Wf, ushort* __restrict__ FrH)
{
  const int t = blockIdx.x * 4 + (threadIdx.x >> 6);
  const int lane = threadIdx.x & 63;
  if (t >= PRE_N) return;
  const int pm6[6]  = {1,2,2,3,3,3}, pl6[6] = {0,0,1,0,1,2};
  const int rm10[10] = {0,1,1,2,2,2,3,3,3,3}, rl10[10] = {0,0,1,0,1,2,0,1,2,3};
  const float* in_wT = xp;
  const float* CwT   = xp + 16384;
  const float* bsT   = xp + 49152;

  const float* pa = nullptr;
  const float* pb = nullptr;
  const float* pn = nullptr;
  float s = 0.f;
  if (t < OFF_GX) {
    pa = in_wT + (t >> 6) * 256; pb = in_wT + (t & 63) * 256;
  } else if (t < OFF_G0) {
    pa = in_wT + (t - OFF_GX) * 256; pb = in_b;
  } else if (t < OFF_WY) {
    if (t == OFF_G0) { pa = in_b; pb = in_b; }
  } else if (t < OFF_WU) {
    const int r = t - OFF_WY, l = r >> 11, qq = r & 2047, c = qq >> 5, n = qq & 31;
    pa = Bw + (l*NS + n)*DM; pn = nsc + l*DM; pb = in_wT + c*256;
  } else if (t < OFF_P) {
    const int r = t - OFF_WU, l = r >> 11, qq = r & 2047, c = qq >> 5, n = qq & 31;
    pa = CwT + (l*32 + n)*256; pb = in_wT + c*256;
  } else if (t < OFF_R) {
    const int r = t - OFF_P, pi = r >> 10, qq = r & 1023, np = qq >> 5, n = qq & 31;
    const int m = pm6[pi], lp = pl6[pi];
    pa = Bw + (m*NS + n)*DM; pn = nsc + m*DM; pb = CwT + (lp*32 + np)*256;
  } else if (t < OFF_CY) {
    const int r = t - OFF_R, ri = r >> 10, qq = r & 1023, np = qq >> 5, n = qq & 31;
    const int m = rm10[ri], lp = rl10[ri];
    pa = CwT + (m*32 + n)*256; pb = CwT + (lp*32 + np)*256;
  } else if (t < OFF_CU) {
    const int r = t - OFF_CY, l = r >> 5, n = r & 31;
    pa = Bw + (l*NS + n)*DM; pn = nsc + l*DM; pb = bsT + l*256;
  } else if (t < OFF_TX) {
    const int r = t - OFF_CU, l = r >> 5, n = r & 31;
    pa = CwT + (l*32 + n)*256; pb = bsT + l*256;
  } else if (t < OFF_TV) {
    const int r = t - OFF_TX, l = r >> 6, i = r & 63;
    pa = Cb + l*DM; pb = in_wT + i*256;
  } else if (t < OFF_CT) {
    const int r = t - OFF_TV, vi = r >> 5, np = r & 31;
    const int m = rm10[vi], lp = rl10[vi];
    pa = Cb + m*DM; pb = CwT + (lp*32 + np)*256;
  } else if (t < OFF_CC) {
    const int l = t - OFF_CT;
    pa = Cb + l*DM; pb = bsT + l*256;
  } else if (t < OFF_AV) {
    const int l = t - OFF_CC;
    pa = Cb + l*DM; pb = Cb + l*DM;
  } else {
    if (lane == 0) s = 1.0f / (1.0f + expf(-logA[t - OFF_AV]));
  }
  if (pa) {
    float4 va = ((const float4*)pa)[lane];
    const float4 vb = ((const float4*)pb)[lane];
    if (pn) {
      const float4 vn = ((const float4*)pn)[lane];
      va.x *= vn.x; va.y *= vn.y; va.z *= vn.z; va.w *= vn.w;
    }
    s = fmaf(va.x, vb.x, fmaf(va.y, vb.y, fmaf(va.z, vb.z, va.w * vb.w)));
  }
  #pragma unroll
  for (int off = 1; off < 64; off <<= 1) s += __shfl_xor(s, off, 64);
  if (lane != 0) return;
  Wf[t] = s;

  // ---- direct fragment packing (identical mapping to r11-15, verified) ----
  if (t < OFF_GX) {                      // G [64][64]
    const int kk = t >> 6, n = t & 63;
    const int u = (kk >> 5)*4 + (n >> 4);
    const int ln2 = (((kk & 31) >> 3) << 4) + (n & 15);
    FrH[(u*256 + ln2*4 + ((kk & 7) >> 1))*2 + (kk & 1)] = f2h(s);
  } else if (t >= OFF_WY && t < OFF_WU) {   // WY [4][64][32]
    const int r = t - OFF_WY, l = r >> 11, kk = (r & 2047) >> 5, n = r & 31;
    const int u = 8 + l*4 + (kk >> 5)*2 + (n >> 4);
    const int ln2 = (((kk & 31) >> 3) << 4) + (n & 15);
    FrH[(u*256 + ln2*4 + ((kk & 7) >> 1))*2 + (kk & 1)] = f2h(s);
  } else if (t >= OFF_WU && t < OFF_P) {    // WU [4][64][32]
    const int r = t - OFF_WU, l = r >> 11, kk = (r & 2047) >> 5, n = r & 31;
    const int u = 24 + l*4 + (kk >> 5)*2 + (n >> 4);
    const int ln2 = (((kk & 31) >> 3) << 4) + (n & 15);
    FrH[(u*256 + ln2*4 + ((kk & 7) >> 1))*2 + (kk & 1)] = f2h(s);
  } else if (t >= OFF_P && t < OFF_R) {     // P [6][32][32]
    const int r = t - OFF_P, pi = r >> 10, kk = (r & 1023) >> 5, n = r & 31;
    const int u = 40 + pi*2 + (n >> 4);
    const int ln2 = ((kk >> 3) << 4) + (n & 15);
    FrH[(u*256 + ln2*4 + ((kk & 7) >> 1))*2 + (kk & 1)] = f2h(s);
  } else if (t >= OFF_R && t < OFF_CY) {    // R [10][32][32], self x0.5
    const int r = t - OFF_R, ri = r >> 10, kk = (r & 1023) >> 5, n = r & 31;
    const int u = 52 + ri*2 + (n >> 4);
    const int ln2 = ((kk >> 3) << 4) + (n & 15);
    const float sc = (ri == 0 || ri == 2 || ri == 5 || ri == 9) ? 0.5f : 1.f;
    FrH[(u*256 + ln2*4 + ((kk & 7) >> 1))*2 + (kk & 1)] = f2h(s * sc);
  } else if (t >= OFF_TX && t < OFF_TV) {   // TX packed pairs
    const int r = t - OFF_TX, l = r >> 6, i = r & 63;
    FrH[(TXOFF + l*32 + (i >> 1))*2 + (i & 1)] = f2h(s);
  } else if (t >= OFF_TV && t < OFF_CT) {   // TV packed pairs
    const int r = t - OFF_TV, vi = r >> 5, nn = r & 31;
    FrH[(TVOFF + vi*16 + (nn >> 1))*2 + (nn & 1)] = f2h(s);
  }
}

// ---------------------------------------------------------------------------
// Per-layer body: Y MFMA -> D write (slot L) -> in-place scan -> U MFMA -> nq.
// 3 Mtiles per wave (rows wid*48 .. wid*48+47).  [verified r13/r15]
// ---------------------------------------------------------------------------
template<int L>
__device__ __forceinline__ void layer_mfma(
    const int tid, const int lane, const int wid, const int s0base,
    uint* lds, const float* __restrict__ Wf, const uint* __restrict__ Fr,
    const float* __restrict__ Bb,
    const uv4 (&xf)[3][2], uv4 (&sf0)[3], uv4 (&sf1)[3], uv4 (&sf2)[3], uv4 (&sf3)[3])
{
  constexpr int RB = L * (L + 1) / 2;
  constexpr int PB = (L == 1) ? 0 : (L == 2) ? 1 : 3;
  constexpr int SL = LS0 + L * 3264;
  float*  ldsF = (float*)lds;
  ushort* ldsH = (ushort*)lds;
  const int li = lane & 15, q4 = (lane >> 4) & 3;

  float cy[2], bb2[2], cu[2], tvs[2];
  #pragma unroll
  for (int nt = 0; nt < 2; ++nt) {
    const int nn = nt*16 + li;
    cy[nt]  = Wf[OFF_CY + L*32 + nn];
    bb2[nt] = Bb[L*32 + nn];
    cu[nt]  = Wf[OFF_CU + L*32 + nn];
    tvs[nt] = Wf[OFF_TV + (RB + L)*32 + nn];
  }
  float invv[3][4];
  #pragma unroll
  for (int m = 0; m < 3; ++m)
    #pragma unroll
    for (int r = 0; r < 4; ++r) {
      const int tk = wid*48 + m*16 + q4*4 + r;
      invv[m][r] = 1.0f / (sqrtf(fmaxf(ldsF[LNQ + tk], 0.f)) * 0.0625f + 1e-8f);
    }

  // ---- Y phase + D write (into slot L) ----
  #pragma unroll
  for (int nt = 0; nt < 2; ++nt) {
    const uv4 by0 = ldB(Fr, 8 + L*4 + 0*2 + nt, lane);
    const uv4 by1 = ldB(Fr, 8 + L*4 + 1*2 + nt, lane);
    uv4 bp0, bp1, bp2;
    if constexpr (L > 0) bp0 = ldB(Fr, 40 + (PB + 0)*2 + nt, lane);
    if constexpr (L > 1) bp1 = ldB(Fr, 40 + (PB + 1)*2 + nt, lane);
    if constexpr (L > 2) bp2 = ldB(Fr, 40 + (PB + 2)*2 + nt, lane);
    #pragma unroll
    for (int m = 0; m < 3; ++m) {
      f32x4 c = {cy[nt], cy[nt], cy[nt], cy[nt]};
      c = MF(xf[m][0], by0, c);
      c = MF(xf[m][1], by1, c);
      if constexpr (L > 0) c = MF(sf0[m], bp0, c);
      if constexpr (L > 1) c = MF(sf1[m], bp1, c);
      if constexpr (L > 2) c = MF(sf2[m], bp2, c);
      #pragma unroll
      for (int r = 0; r < 4; ++r) {
        const int tk = wid*48 + m*16 + q4*4 + r;
        const bool valid = (s0base > 0) || (tk >= NWARM);
        const float v = valid ? fmaf(invv[m][r], c[r], bb2[nt]) : 0.f;
        ldsH[SL*2 + tk*34 + nt*16 + li] = f2h(v);
      }
    }
  }
  __syncthreads();   // B1: D visible

  // ---- in-place scan: 8 groups of 24 tokens; stage-1 regs then Horner ----
  const int n = tid & 31, g = tid >> 5;
  const float a = Wf[OFF_AV + L*32 + n];
  float dv[HIST + 24];
  #pragma unroll
  for (int k = 0; k < HIST + 24; ++k) {
    const int p = g*24 - HIST + k;
    dv[k] = (p >= 0) ? h2f(ldsH[SL*2 + p*34 + n]) : 0.f;
  }
  __syncthreads();   // B2: all D reads complete before s overwrites

  {
    float carry = 0.f;
    #pragma unroll
    for (int k = 0; k < HIST + 24; ++k) {
      carry = fmaf(a, carry, dv[k]);
      if (k >= HIST) ldsH[SL*2 + (g*24 + k - HIST)*34 + n] = f2h(carry);
    }
  }
  // ---- tl per token (x + slots lp<L; none touches slot L) ----
  if (tid < PIPE) {
    float tl = Wf[OFF_CT + L];
    const uint* xr = lds + LX + tid*34;
    #pragma unroll 8
    for (int c2 = 0; c2 < 32; ++c2) tl = fdot2h(Fr[TXOFF + L*32 + c2], xr[c2], tl);
    if constexpr (L > 0) { const uint* sr = lds + LS0 + 0*3264 + tid*17;
      #pragma unroll
      for (int m2 = 0; m2 < 16; ++m2) tl = fdot2h(Fr[TVOFF + (RB+0)*16 + m2], sr[m2], tl); }
    if constexpr (L > 1) { const uint* sr = lds + LS0 + 1*3264 + tid*17;
      #pragma unroll
      for (int m2 = 0; m2 < 16; ++m2) tl = fdot2h(Fr[TVOFF + (RB+1)*16 + m2], sr[m2], tl); }
    if constexpr (L > 2) { const uint* sr = lds + LS0 + 2*3264 + tid*17;
      #pragma unroll
      for (int m2 = 0; m2 < 16; ++m2) tl = fdot2h(Fr[TVOFF + (RB+2)*16 + m2], sr[m2], tl); }
    ldsF[LTL + tid] = tl;
  }
  __syncthreads();   // B3: s + tl visible

  // ---- load S_L A-frags ----
  uv4 sA[3];
  #pragma unroll
  for (int m = 0; m < 3; ++m) {
    const uint* p = lds + SL + (wid*48 + m*16 + li)*17 + q4*4;
    uv4 v; v[0] = p[0]; v[1] = p[1]; v[2] = p[2]; v[3] = p[3];
    sA[m] = v;
  }
  if constexpr (L == 0)      { sf0[0] = sA[0]; sf0[1] = sA[1]; sf0[2] = sA[2]; }
  else if constexpr (L == 1) { sf1[0] = sA[0]; sf1[1] = sA[1]; sf1[2] = sA[2]; }
  else if constexpr (L == 2) { sf2[0] = sA[0]; sf2[1] = sA[1]; sf2[2] = sA[2]; }
  else                       { sf3[0] = sA[0]; sf3[1] = sA[1]; sf3[2] = sA[2]; }

  // ---- U/ACC phase + w row-dot ----
  float wv[3][4] = {{0,0,0,0},{0,0,0,0},{0,0,0,0}};
  #pragma unroll
  for (int nt = 0; nt < 2; ++nt) {
    const uv4 bu0 = ldB(Fr, 24 + L*4 + 0*2 + nt, lane);
    const uv4 bu1 = ldB(Fr, 24 + L*4 + 1*2 + nt, lane);
    uv4 br0, br1, br2;
    if constexpr (L > 0) br0 = ldB(Fr, 52 + (RB + 0)*2 + nt, lane);
    if constexpr (L > 1) br1 = ldB(Fr, 52 + (RB + 1)*2 + nt, lane);
    if constexpr (L > 2) br2 = ldB(Fr, 52 + (RB + 2)*2 + nt, lane);
    const uv4 brS = ldB(Fr, 52 + (RB + L)*2 + nt, lane);   // 0.5*R_self
    #pragma unroll
    for (int m = 0; m < 3; ++m) {
      f32x4 c = {0.f, 0.f, 0.f, 0.f};
      c = MF(xf[m][0], bu0, c);
      c = MF(xf[m][1], bu1, c);
      if constexpr (L > 0) c = MF(sf0[m], br0, c);
      if constexpr (L > 1) c = MF(sf1[m], br1, c);
      if constexpr (L > 2) c = MF(sf2[m], br2, c);
      c = MF(sA[m], brS, c);
      #pragma unroll
      for (int r = 0; r < 4; ++r) {
        const int tk = wid*48 + m*16 + q4*4 + r;
        const float sv = h2f(ldsH[SL*2 + tk*34 + nt*16 + li]);
        wv[m][r] = fmaf(c[r] + cu[nt] + tvs[nt], sv, wv[m][r]);
      }
    }
  }
  #pragma unroll
  for (int m = 0; m < 3; ++m)
    #pragma unroll
    for (int r = 0; r < 4; ++r) {
      float v = wv[m][r];
      v += __shfl_xor(v, 1, 64); v += __shfl_xor(v, 2, 64);
      v += __shfl_xor(v, 4, 64); v += __shfl_xor(v, 8, 64);
      wv[m][r] = v;
    }
  if (li == 0) {
    #pragma unroll
    for (int m = 0; m < 3; ++m)
      #pragma unroll
      for (int r = 0; r < 4; ++r) {
        const int tk = wid*48 + m*16 + q4*4 + r;
        ldsF[LNQ + tk] += 2.f * (wv[m][r] + ldsF[LTL + tk]);
      }
  }
  __syncthreads();   // B4: nq updated
}

// ---------------------------------------------------------------------------
// Main kernel (MFMA engine; grid 512 = exactly 2 blocks/CU).  [verified r15]
// ---------------------------------------------------------------------------
__global__ __launch_bounds__(NTHR, 2) void ssm_main(
    const float* __restrict__ x, const float* __restrict__ Wf,
    const uint* __restrict__ Fr, const float* __restrict__ Bb,
    float* __restrict__ part)
{
  extern __shared__ uint lds[];
  float*  ldsF = (float*)lds;
  ushort* ldsH = (ushort*)lds;
  const int tid = threadIdx.x;
  const int lane = tid & 63, wid = tid >> 6;
  const int li = lane & 15, q4 = (lane >> 4) & 3;
  const int blk = blockIdx.x;
  const int bb = blk >> 6;                 // 64 chunks per sequence
  const int s0base = (blk & 63) * TOUT;

  // ---- stage x -> fp16 LDS rows [192][34] ----
  {
    const float4* xg4 = (const float4*)(x + (size_t)bb * S_ * DIN);
    #pragma unroll
    for (int k = 0; k < 12; ++k) {
      const int idx = k * NTHR + tid;
      const int tok = idx >> 4, c4 = idx & 15;
      const int lt = s0base - NWARM + tok;
      float4 v = make_float4(0.f, 0.f, 0.f, 0.f);
      if (lt >= 0) v = xg4[lt * 16 + c4];
      lds[LX + tok*34 + 2*c4]     = pack2(v.x, v.y);
      lds[LX + tok*34 + 2*c4 + 1] = pack2(v.z, v.w);
    }
  }
  __syncthreads();

  // ---- X A-frags (resident) ----
  uv4 xf[3][2];
  #pragma unroll
  for (int m = 0; m < 3; ++m)
    #pragma unroll
    for (int k = 0; k < 2; ++k) {
      const uint* p = lds + LX + (wid*48 + m*16 + li)*34 + k*16 + q4*4;
      uv4 v; v[0] = p[0]; v[1] = p[1]; v[2] = p[2]; v[3] = p[3];
      xf[m][k] = v;
    }

  // ---- nq0 = g0 + 2 gx.x + x^T G x ----
  {
    float val[3][4] = {{0,0,0,0},{0,0,0,0},{0,0,0,0}};
    #pragma unroll
    for (int nt = 0; nt < 4; ++nt) {
      const float gxv = 2.f * Wf[OFF_GX + nt*16 + li];
      const uv4 bg0 = ldB(Fr, 0*4 + nt, lane);
      const uv4 bg1 = ldB(Fr, 1*4 + nt, lane);
      #pragma unroll
      for (int m = 0; m < 3; ++m) {
        f32x4 c = {gxv, gxv, gxv, gxv};
        c = MF(xf[m][0], bg0, c);
        c = MF(xf[m][1], bg1, c);
        #pragma unroll
        for (int r = 0; r < 4; ++r) {
          const int tk = wid*48 + m*16 + q4*4 + r;
          const float xv = h2f(ldsH[tk*68 + nt*16 + li]);
          val[m][r] = fmaf(c[r], xv, val[m][r]);
        }
      }
    }
    const float g0 = Wf[OFF_G0];
    #pragma unroll
    for (int m = 0; m < 3; ++m)
      #pragma unroll
      for (int r = 0; r < 4; ++r) {
        float v = val[m][r];
        v += __shfl_xor(v, 1, 64); v += __shfl_xor(v, 2, 64);
        v += __shfl_xor(v, 4, 64); v += __shfl_xor(v, 8, 64);
        if (li == 0) ldsF[LNQ + wid*48 + m*16 + q4*4 + r] = g0 + v;
      }
  }
  __syncthreads();

  // ---- layers ----
  uv4 sf0[3], sf1[3], sf2[3], sf3[3];
  layer_mfma<0>(tid, lane, wid, s0base, lds, Wf, Fr, Bb, xf, sf0, sf1, sf2, sf3);
  layer_mfma<1>(tid, lane, wid, s0base, lds, Wf, Fr, Bb, xf, sf0, sf1, sf2, sf3);
  layer_mfma<2>(tid, lane, wid, s0base, lds, Wf, Fr, Bb, xf, sf0, sf1, sf2, sf3);
  layer_mfma<3>(tid, lane, wid, s0base, lds, Wf, Fr, Bb, xf, sf0, sf1, sf2, sf3);

  // ---- final r + block partial sums (6 narrow passes over dead x region) ----
  float rr = 0.f;
  if (tid >= NWARM && tid < PIPE)
    rr = 1.0f / (sqrtf(fmaxf(ldsF[LNQ + tid], 0.f)) * 0.0625f + 1e-8f);
  const int jj = tid - NWARM;             // 0..127 for output tokens
  float* pf = (float*)lds;                // overlays x (dead)

  // pass A1: [r | x0..31 * r]
  if (tid >= NWARM && tid < PIPE) {
    pf[jj*33] = rr;
    const float4* xr4 = (const float4*)(x + ((size_t)bb * S_ + (size_t)(s0base + jj)) * DIN);
    #pragma unroll
    for (int c4 = 0; c4 < 8; ++c4) {
      const float4 v = xr4[c4];
      pf[jj*33 + 1 + 4*c4] = v.x * rr; pf[jj*33 + 2 + 4*c4] = v.y * rr;
      pf[jj*33 + 3 + 4*c4] = v.z * rr; pf[jj*33 + 4 + 4*c4] = v.w * rr;
    }
  }
  __syncthreads();
  if (tid < 33) { float s = 0.f;
    for (int k = 0; k < TOUT; ++k) s += pf[k*33 + tid];
    part[blk*193 + tid] = s; }
  __syncthreads();
  // pass A2: x32..63 * r
  if (tid >= NWARM && tid < PIPE) {
    const float4* xr4 = (const float4*)(x + ((size_t)bb * S_ + (size_t)(s0base + jj)) * DIN);
    #pragma unroll
    for (int c4 = 8; c4 < 16; ++c4) {
      const float4 v = xr4[c4];
      const int o = 4*c4 - 32;
      pf[jj*33 + o]     = v.x * rr; pf[jj*33 + o + 1] = v.y * rr;
      pf[jj*33 + o + 2] = v.z * rr; pf[jj*33 + o + 3] = v.w * rr;
    }
  }
  __syncthreads();
  if (tid < 32) { float s = 0.f;
    for (int k = 0; k < TOUT; ++k) s += pf[k*33 + tid];
    part[blk*193 + 33 + tid] = s; }
  __syncthreads();
  // passes B..E: s_l * r
  for (int l = 0; l < 4; ++l) {
    if (tid >= NWARM && tid < PIPE) {
      #pragma unroll
      for (int m2 = 0; m2 < 16; ++m2) {
        const uint w = lds[LS0 + l*3264 + tid*17 + m2];
        pf[jj*33 + 2*m2]     = h2f((ushort)(w & 0xffffu)) * rr;
        pf[jj*33 + 2*m2 + 1] = h2f((ushort)(w >> 16)) * rr;
      }
    }
    __syncthreads();
    if (tid < 32) { float s = 0.f;
      for (int k = 0; k < TOUT; ++k) s += pf[k*33 + tid];
      part[blk*193 + 65 + l*32 + tid] = s; }
    __syncthreads();
  }
}

// ---------------------------------------------------------------------------
// Final: reduce partials (64 rows/batch, 4-way ILP), mean, classifier MLP.
// ---------------------------------------------------------------------------
__global__ __launch_bounds__(256) void ssm_final(
    const float* __restrict__ part,
    const float* __restrict__ in_w, const float* __restrict__ in_b,
    const float* __restrict__ Cw, const float* __restrict__ Cb,
    const float* __restrict__ fsc,
    const float* __restrict__ w1, const float* __restrict__ b1,
    const float* __restrict__ w2, const float* __restrict__ b2,
    float* __restrict__ out)
{
  const int b = blockIdx.x, t = threadIdx.x;
  __shared__ float red[193];
  __shared__ float meanv[DM];
  __shared__ float h1[DM];
  if (t < 193) {
    float a0 = 0.f, a1 = 0.f, a2 = 0.f, a3 = 0.f;
    const float* pp = part + (size_t)b * 64 * 193 + t;
    for (int k = 0; k < 64; k += 4) {
      a0 += pp[(k + 0) * 193]; a1 += pp[(k + 1) * 193];
      a2 += pp[(k + 2) * 193]; a3 += pp[(k + 3) * 193];
    }
    red[t] = (a0 + a1) + (a2 + a3);
  }
  __syncthreads();
  {
    const float rho = red[0];
    float m = in_b[t] * rho;
    #pragma unroll 4
    for (int i = 0; i < 64; ++i) m = fmaf(in_w[t*64 + i], red[1 + i], m);
    for (int l = 0; l < NL; ++l) {
      #pragma unroll 4
      for (int n = 0; n < 32; ++n)
        m = fmaf(Cw[(l*DM + t)*NS + n], red[65 + l*32 + n], m);
      m = fmaf(Cb[l*DM + t], rho, m);
    }
    meanv[t] = fsc[t] * m * (1.0f / (float)S_);
  }
  __syncthreads();
  {
    float z = b1[t];
    for (int e = 0; e < DM; ++e) z = fmaf(w1[t*DM + e], meanv[e], z);
    h1[t] = z / (1.0f + expf(-z));
  }
  __syncthreads();
  if (t < 10) {
    float lg = b2[t];
    for (int e = 0; e < DM; ++e) lg = fmaf(w2[t*DM + e], h1[e], lg);
    out[b*10 + t] = lg;
  }
}

// ---------------------------------------------------------------------------
extern "C" void kernel_launch(void* const* d_in, const int* in_sizes, int n_in,
                              void* d_out, int out_size, void* d_ws, size_t ws_size,
                              hipStream_t stream)
{
  const float* x    = (const float*)d_in[0];
  const float* in_w = (const float*)d_in[1];
  const float* in_b = (const float*)d_in[2];
  const float* logA = (const float*)d_in[3];
  const float* Bw   = (const float*)d_in[4];
  const float* Bb   = (const float*)d_in[5];
  const float* Cw   = (const float*)d_in[6];
  const float* Cb   = (const float*)d_in[7];
  const float* nsc  = (const float*)d_in[8];
  const float* fsc  = (const float*)d_in[9];
  const float* w1   = (const float*)d_in[10];
  const float* b1   = (const float*)d_in[11];
  const float* w2   = (const float*)d_in[12];
  const float* b2   = (const float*)d_in[13];
  float* out  = (float*)d_out;
  float* wsf  = (float*)d_ws;
  uint*  Fr   = (uint*)(wsf + WS_FRAG);
  float* part = wsf + WS_PART;
  float* xp   = wsf + WS_XP;
  (void)in_sizes; (void)n_in; (void)out_size; (void)ws_size;

  ssm_xpose<<<196, 256, 0, stream>>>(in_w, Cw, in_b, Cb, xp);
  ssm_prep<<<(PRE_N + 3) / 4, 256, 0, stream>>>(logA, Bw, nsc, in_b, Cb, xp,
                                                wsf, (ushort*)Fr);
  ssm_main<<<NBLK, NTHR, LDSN * sizeof(uint), stream>>>(x, wsf, Fr, Bb, part);
  ssm_final<<<B_, 256, 0, stream>>>(part, in_w, in_b, Cw, Cb, fsc, w1, b1, w2, b2, out);
}

// Round 17
// 77.079 us; speedup vs baseline: 1.3966x; 1.0045x over previous
//
#include <hip/hip_runtime.h>
#include <hip/hip_fp16.h>
#include <math.h>

#define B_    8
#define S_    8192
#define DIN   64
#define DM    256
#define NS    32
#define NL    4
#define TOUT  128
#define NWARM 64
#define PIPE  192            // 64 warm + 128 out
#define HIST  16             // scan window; a^17 ~ 7e-9
#define NBLK  512            // B_*S_/TOUT -> exactly 2 blocks/CU, zero tail
#define NTHR  384            // 6 waves; 2 Mtiles (32 tokens) per wave

// ---- fp32 precomputed-weight offsets (Wf) ----
#define OFF_G   0
#define OFF_GX  4096
#define OFF_G0  4160
#define OFF_WY  4224
#define OFF_WU  12416
#define OFF_P   20608
#define OFF_R   26752
#define OFF_CY  36992
#define OFF_CU  37120
#define OFF_TX  37248
#define OFF_TV  37504
#define OFF_CT  37824
#define OFF_CC  37828
#define OFF_AV  37832
#define PRE_N   37960

// ---- frag buffer (u32 units). 72 frag-units of 256 u32 + TX/TV tails ----
#define TXOFF  18432         // 4*32 u32
#define TVOFF  18560         // 10*16 u32
#define WS_FRAG 40960        // float offset of Fr in ws
#define WS_PART 65536        // float offset of part[512][193]
#define WS_XP   165888       // float offset of transposed staging
//   in_wT [64][256] at +0, CwT [128][256] at +16384, bsT [4][256] at +49152

// ---- LDS u32 layout: x[192][34] | slots[4][192][17] | nq | tl ----
#define LX    0
#define LS0   6528           // slot L: LS0 + L*3264
#define LNQ   19584          // float[192]
#define LTL   19776          // float[192]
#define LDSN  19968          // 79,872 B -> 2 blocks/CU

typedef _Float16 h2_t  __attribute__((ext_vector_type(2)));
typedef _Float16 f16x8 __attribute__((ext_vector_type(8)));
typedef float    f32x4 __attribute__((ext_vector_type(4)));
typedef uint     uv4   __attribute__((ext_vector_type(4)));

__device__ __forceinline__ float h2f(ushort u) { return __half2float(__ushort_as_half(u)); }
__device__ __forceinline__ ushort f2h(float f) { return __half_as_ushort(__float2half(f)); }
__device__ __forceinline__ uint pack2(float a, float b) {
  return (uint)f2h(a) | ((uint)f2h(b) << 16);
}
__device__ __forceinline__ float fdot2h(uint w, uint v, float c) {
  return __builtin_amdgcn_fdot2(__builtin_bit_cast(h2_t, w),
                                __builtin_bit_cast(h2_t, v), c, false);
}
__device__ __forceinline__ f32x4 MF(uv4 a, uv4 b, f32x4 c) {
  return __builtin_amdgcn_mfma_f32_16x16x32_f16(
      __builtin_bit_cast(f16x8, a), __builtin_bit_cast(f16x8, b), c, 0, 0, 0);
}
__device__ __forceinline__ uv4 ldB(const uint* __restrict__ Fr, int unit, int lane) {
  return ((const uv4*)Fr)[unit * 64 + lane];
}

// ---------------------------------------------------------------------------
// Xpose: materialize contiguous-over-d rows for prep's column operands.
// ---------------------------------------------------------------------------
__global__ void ssm_xpose(const float* __restrict__ in_w, const float* __restrict__ Cw,
                          const float* __restrict__ in_b, const float* __restrict__ Cb,
                          float* __restrict__ xp)
{
  const int g = blockIdx.x * 256 + threadIdx.x;
  if (g < 64 * 256) {
    const int i = g >> 8, d = g & 255;
    xp[g] = in_w[d * 64 + i];
  } else if (g < 64 * 256 + 128 * 256) {
    const int r = g - 64 * 256, ln = r >> 8, d = r & 255;
    const int l = ln >> 5, n = ln & 31;
    xp[16384 + r] = Cw[(l * DM + d) * NS + n];
  } else if (g < 64 * 256 + 128 * 256 + 4 * 256) {
    const int r = g - (64 * 256 + 128 * 256), l = r >> 8, d = r & 255;
    float bs = in_b[d];
    for (int lp = 0; lp < l; ++lp) bs += Cb[lp * DM + d];
    xp[49152 + r] = bs;
  }
}

// ---------------------------------------------------------------------------
// Prep: wave-per-output; all operand reads contiguous over d (float4/lane).
// ---------------------------------------------------------------------------
__global__ __launch_bounds__(256) void ssm_prep(
    const float* __restrict__ logA, const float* __restrict__ Bw,
    const float* __restrict__ nsc, const float* __restrict__ in_b,
    const float* __restrict__ Cb, const float* __restrict__ xp,
    float* __restrict__ Wf, ushort* __restrict__ FrH)
{
  const int t = blockIdx.x * 4 + (threadIdx.x >> 6);
  const int lane = threadIdx.x & 63;
  if (t >= PRE_N) return;
  const int pm6[6]  = {1,2,2,3,3,3}, pl6[6] = {0,0,1,0,1,2};
  const int rm10[10] = {0,1,1,2,2,2,3,3,3,3}, rl10[10] = {0,0,1,0,1,2,0,1,2,3};
  const float* in_wT = xp;
  const float* CwT   = xp + 16384;
  const float* bsT   = xp + 49152;

  const float* pa = nullptr;
  const float* pb = nullptr;
  const float* pn = nullptr;
  float s = 0.f;
  if (t < OFF_GX) {
    pa = in_wT + (t >> 6) * 256; pb = in_wT + (t & 63) * 256;
  } else if (t < OFF_G0) {
    pa = in_wT + (t - OFF_GX) * 256; pb = in_b;
  } else if (t < OFF_WY) {
    if (t == OFF_G0) { pa = in_b; pb = in_b; }
  } else if (t < OFF_WU) {
    const int r = t - OFF_WY, l = r >> 11, qq = r & 2047, c = qq >> 5, n = qq & 31;
    pa = Bw + (l*NS + n)*DM; pn = nsc + l*DM; pb = in_wT + c*256;
  } else if (t < OFF_P) {
    const int r = t - OFF_WU, l = r >> 11, qq = r & 2047, c = qq >> 5, n = qq & 31;
    pa = CwT + (l*32 + n)*256; pb = in_wT + c*256;
  } else if (t < OFF_R) {
    const int r = t - OFF_P, pi = r >> 10, qq = r & 1023, np = qq >> 5, n = qq & 31;
    const int m = pm6[pi], lp = pl6[pi];
    pa = Bw + (m*NS + n)*DM; pn = nsc + m*DM; pb = CwT + (lp*32 + np)*256;
  } else if (t < OFF_CY) {
    const int r = t - OFF_R, ri = r >> 10, qq = r & 1023, np = qq >> 5, n = qq & 31;
    const int m = rm10[ri], lp = rl10[ri];
    pa = CwT + (m*32 + n)*256; pb = CwT + (lp*32 + np)*256;
  } else if (t < OFF_CU) {
    const int r = t - OFF_CY, l = r >> 5, n = r & 31;
    pa = Bw + (l*NS + n)*DM; pn = nsc + l*DM; pb = bsT + l*256;
  } else if (t < OFF_TX) {
    const int r = t - OFF_CU, l = r >> 5, n = r & 31;
    pa = CwT + (l*32 + n)*256; pb = bsT + l*256;
  } else if (t < OFF_TV) {
    const int r = t - OFF_TX, l = r >> 6, i = r & 63;
    pa = Cb + l*DM; pb = in_wT + i*256;
  } else if (t < OFF_CT) {
    const int r = t - OFF_TV, vi = r >> 5, np = r & 31;
    const int m = rm10[vi], lp = rl10[vi];
    pa = Cb + m*DM; pb = CwT + (lp*32 + np)*256;
  } else if (t < OFF_CC) {
    const int l = t - OFF_CT;
    pa = Cb + l*DM; pb = bsT + l*256;
  } else if (t < OFF_AV) {
    const int l = t - OFF_CC;
    pa = Cb + l*DM; pb = Cb + l*DM;
  } else {
    if (lane == 0) s = 1.0f / (1.0f + expf(-logA[t - OFF_AV]));
  }
  if (pa) {
    float4 va = ((const float4*)pa)[lane];
    const float4 vb = ((const float4*)pb)[lane];
    if (pn) {
      const float4 vn = ((const float4*)pn)[lane];
      va.x *= vn.x; va.y *= vn.y; va.z *= vn.z; va.w *= vn.w;
    }
    s = fmaf(va.x, vb.x, fmaf(va.y, vb.y, fmaf(va.z, vb.z, va.w * vb.w)));
  }
  #pragma unroll
  for (int off = 1; off < 64; off <<= 1) s += __shfl_xor(s, off, 64);
  if (lane != 0) return;
  Wf[t] = s;

  // ---- direct fragment packing (identical mapping to r11-16, verified) ----
  if (t < OFF_GX) {                      // G [64][64]
    const int kk = t >> 6, n = t & 63;
    const int u = (kk >> 5)*4 + (n >> 4);
    const int ln2 = (((kk & 31) >> 3) << 4) + (n & 15);
    FrH[(u*256 + ln2*4 + ((kk & 7) >> 1))*2 + (kk & 1)] = f2h(s);
  } else if (t >= OFF_WY && t < OFF_WU) {   // WY [4][64][32]
    const int r = t - OFF_WY, l = r >> 11, kk = (r & 2047) >> 5, n = r & 31;
    const int u = 8 + l*4 + (kk >> 5)*2 + (n >> 4);
    const int ln2 = (((kk & 31) >> 3) << 4) + (n & 15);
    FrH[(u*256 + ln2*4 + ((kk & 7) >> 1))*2 + (kk & 1)] = f2h(s);
  } else if (t >= OFF_WU && t < OFF_P) {    // WU [4][64][32]
    const int r = t - OFF_WU, l = r >> 11, kk = (r & 2047) >> 5, n = r & 31;
    const int u = 24 + l*4 + (kk >> 5)*2 + (n >> 4);
    const int ln2 = (((kk & 31) >> 3) << 4) + (n & 15);
    FrH[(u*256 + ln2*4 + ((kk & 7) >> 1))*2 + (kk & 1)] = f2h(s);
  } else if (t >= OFF_P && t < OFF_R) {     // P [6][32][32]
    const int r = t - OFF_P, pi = r >> 10, kk = (r & 1023) >> 5, n = r & 31;
    const int u = 40 + pi*2 + (n >> 4);
    const int ln2 = ((kk >> 3) << 4) + (n & 15);
    FrH[(u*256 + ln2*4 + ((kk & 7) >> 1))*2 + (kk & 1)] = f2h(s);
  } else if (t >= OFF_R && t < OFF_CY) {    // R [10][32][32], self x0.5
    const int r = t - OFF_R, ri = r >> 10, kk = (r & 1023) >> 5, n = r & 31;
    const int u = 52 + ri*2 + (n >> 4);
    const int ln2 = ((kk >> 3) << 4) + (n & 15);
    const float sc = (ri == 0 || ri == 2 || ri == 5 || ri == 9) ? 0.5f : 1.f;
    FrH[(u*256 + ln2*4 + ((kk & 7) >> 1))*2 + (kk & 1)] = f2h(s * sc);
  } else if (t >= OFF_TX && t < OFF_TV) {   // TX packed pairs
    const int r = t - OFF_TX, l = r >> 6, i = r & 63;
    FrH[(TXOFF + l*32 + (i >> 1))*2 + (i & 1)] = f2h(s);
  } else if (t >= OFF_TV && t < OFF_CT) {   // TV packed pairs
    const int r = t - OFF_TV, vi = r >> 5, nn = r & 31;
    FrH[(TVOFF + vi*16 + (nn >> 1))*2 + (nn & 1)] = f2h(s);
  }
}

// ---------------------------------------------------------------------------
// Per-layer body: Y MFMA -> D write (slot L) -> in-place scan -> U MFMA -> nq.
// 6 waves x 2 Mtiles (rows wid*32 .. wid*32+31).
// ---------------------------------------------------------------------------
template<int L>
__device__ __forceinline__ void layer_mfma(
    const int tid, const int lane, const int wid, const int s0base,
    uint* lds, const float* __restrict__ Wf, const uint* __restrict__ Fr,
    const float* __restrict__ Bb,
    const uv4 (&xf)[2][2], uv4 (&sf0)[2], uv4 (&sf1)[2], uv4 (&sf2)[2], uv4 (&sf3)[2])
{
  constexpr int RB = L * (L + 1) / 2;
  constexpr int PB = (L == 1) ? 0 : (L == 2) ? 1 : 3;
  constexpr int SL = LS0 + L * 3264;
  float*  ldsF = (float*)lds;
  ushort* ldsH = (ushort*)lds;
  const int li = lane & 15, q4 = (lane >> 4) & 3;

  float cy[2], bb2[2], cu[2], tvs[2];
  #pragma unroll
  for (int nt = 0; nt < 2; ++nt) {
    const int nn = nt*16 + li;
    cy[nt]  = Wf[OFF_CY + L*32 + nn];
    bb2[nt] = Bb[L*32 + nn];
    cu[nt]  = Wf[OFF_CU + L*32 + nn];
    tvs[nt] = Wf[OFF_TV + (RB + L)*32 + nn];
  }
  float invv[2][4];
  #pragma unroll
  for (int m = 0; m < 2; ++m)
    #pragma unroll
    for (int r = 0; r < 4; ++r) {
      const int tk = wid*32 + m*16 + q4*4 + r;
      invv[m][r] = 1.0f / (sqrtf(fmaxf(ldsF[LNQ + tk], 0.f)) * 0.0625f + 1e-8f);
    }

  // ---- Y phase + D write (into slot L) ----
  #pragma unroll
  for (int nt = 0; nt < 2; ++nt) {
    const uv4 by0 = ldB(Fr, 8 + L*4 + 0*2 + nt, lane);
    const uv4 by1 = ldB(Fr, 8 + L*4 + 1*2 + nt, lane);
    uv4 bp0, bp1, bp2;
    if constexpr (L > 0) bp0 = ldB(Fr, 40 + (PB + 0)*2 + nt, lane);
    if constexpr (L > 1) bp1 = ldB(Fr, 40 + (PB + 1)*2 + nt, lane);
    if constexpr (L > 2) bp2 = ldB(Fr, 40 + (PB + 2)*2 + nt, lane);
    #pragma unroll
    for (int m = 0; m < 2; ++m) {
      f32x4 c = {cy[nt], cy[nt], cy[nt], cy[nt]};
      c = MF(xf[m][0], by0, c);
      c = MF(xf[m][1], by1, c);
      if constexpr (L > 0) c = MF(sf0[m], bp0, c);
      if constexpr (L > 1) c = MF(sf1[m], bp1, c);
      if constexpr (L > 2) c = MF(sf2[m], bp2, c);
      #pragma unroll
      for (int r = 0; r < 4; ++r) {
        const int tk = wid*32 + m*16 + q4*4 + r;
        const bool valid = (s0base > 0) || (tk >= NWARM);
        const float v = valid ? fmaf(invv[m][r], c[r], bb2[nt]) : 0.f;
        ldsH[SL*2 + tk*34 + nt*16 + li] = f2h(v);
      }
    }
  }
  __syncthreads();   // B1: D visible

  // ---- in-place scan: 12 groups of 16 tokens; stage-1 regs then Horner ----
  const int n = tid & 31, g = tid >> 5;
  const float a = Wf[OFF_AV + L*32 + n];
  float dv[HIST + 16];
  #pragma unroll
  for (int k = 0; k < HIST + 16; ++k) {
    const int p = g*16 - HIST + k;
    dv[k] = (p >= 0) ? h2f(ldsH[SL*2 + p*34 + n]) : 0.f;
  }
  __syncthreads();   // B2: all D reads complete before s overwrites

  {
    float carry = 0.f;
    #pragma unroll
    for (int k = 0; k < HIST + 16; ++k) {
      carry = fmaf(a, carry, dv[k]);
      if (k >= HIST) ldsH[SL*2 + (g*16 + k - HIST)*34 + n] = f2h(carry);
    }
  }
  // ---- tl per token (x + slots lp<L; none touches slot L) ----
  if (tid < PIPE) {
    float tl = Wf[OFF_CT + L];
    const uint* xr = lds + LX + tid*34;
    #pragma unroll 8
    for (int c2 = 0; c2 < 32; ++c2) tl = fdot2h(Fr[TXOFF + L*32 + c2], xr[c2], tl);
    if constexpr (L > 0) { const uint* sr = lds + LS0 + 0*3264 + tid*17;
      #pragma unroll
      for (int m2 = 0; m2 < 16; ++m2) tl = fdot2h(Fr[TVOFF + (RB+0)*16 + m2], sr[m2], tl); }
    if constexpr (L > 1) { const uint* sr = lds + LS0 + 1*3264 + tid*17;
      #pragma unroll
      for (int m2 = 0; m2 < 16; ++m2) tl = fdot2h(Fr[TVOFF + (RB+1)*16 + m2], sr[m2], tl); }
    if constexpr (L > 2) { const uint* sr = lds + LS0 + 2*3264 + tid*17;
      #pragma unroll
      for (int m2 = 0; m2 < 16; ++m2) tl = fdot2h(Fr[TVOFF + (RB+2)*16 + m2], sr[m2], tl); }
    ldsF[LTL + tid] = tl;
  }
  __syncthreads();   // B3: s + tl visible

  // ---- load S_L A-frags ----
  uv4 sA[2];
  #pragma unroll
  for (int m = 0; m < 2; ++m) {
    const uint* p = lds + SL + (wid*32 + m*16 + li)*17 + q4*4;
    uv4 v; v[0] = p[0]; v[1] = p[1]; v[2] = p[2]; v[3] = p[3];
    sA[m] = v;
  }
  if constexpr (L == 0)      { sf0[0] = sA[0]; sf0[1] = sA[1]; }
  else if constexpr (L == 1) { sf1[0] = sA[0]; sf1[1] = sA[1]; }
  else if constexpr (L == 2) { sf2[0] = sA[0]; sf2[1] = sA[1]; }
  else                       { sf3[0] = sA[0]; sf3[1] = sA[1]; }

  // ---- U/ACC phase + w row-dot ----
  float wv[2][4] = {{0,0,0,0},{0,0,0,0}};
  #pragma unroll
  for (int nt = 0; nt < 2; ++nt) {
    const uv4 bu0 = ldB(Fr, 24 + L*4 + 0*2 + nt, lane);
    const uv4 bu1 = ldB(Fr, 24 + L*4 + 1*2 + nt, lane);
    uv4 br0, br1, br2;
    if constexpr (L > 0) br0 = ldB(Fr, 52 + (RB + 0)*2 + nt, lane);
    if constexpr (L > 1) br1 = ldB(Fr, 52 + (RB + 1)*2 + nt, lane);
    if constexpr (L > 2) br2 = ldB(Fr, 52 + (RB + 2)*2 + nt, lane);
    const uv4 brS = ldB(Fr, 52 + (RB + L)*2 + nt, lane);   // 0.5*R_self
    #pragma unroll
    for (int m = 0; m < 2; ++m) {
      f32x4 c = {0.f, 0.f, 0.f, 0.f};
      c = MF(xf[m][0], bu0, c);
      c = MF(xf[m][1], bu1, c);
      if constexpr (L > 0) c = MF(sf0[m], br0, c);
      if constexpr (L > 1) c = MF(sf1[m], br1, c);
      if constexpr (L > 2) c = MF(sf2[m], br2, c);
      c = MF(sA[m], brS, c);
      #pragma unroll
      for (int r = 0; r < 4; ++r) {
        const int tk = wid*32 + m*16 + q4*4 + r;
        const float sv = h2f(ldsH[SL*2 + tk*34 + nt*16 + li]);
        wv[m][r] = fmaf(c[r] + cu[nt] + tvs[nt], sv, wv[m][r]);
      }
    }
  }
  #pragma unroll
  for (int m = 0; m < 2; ++m)
    #pragma unroll
    for (int r = 0; r < 4; ++r) {
      float v = wv[m][r];
      v += __shfl_xor(v, 1, 64); v += __shfl_xor(v, 2, 64);
      v += __shfl_xor(v, 4, 64); v += __shfl_xor(v, 8, 64);
      wv[m][r] = v;
    }
  if (li == 0) {
    #pragma unroll
    for (int m = 0; m < 2; ++m)
      #pragma unroll
      for (int r = 0; r < 4; ++r) {
        const int tk = wid*32 + m*16 + q4*4 + r;
        ldsF[LNQ + tk] += 2.f * (wv[m][r] + ldsF[LTL + tk]);
      }
  }
  __syncthreads();   // B4: nq updated
}

// ---------------------------------------------------------------------------
// Main kernel (MFMA engine; grid 512 = 2 blocks/CU, 6 waves each).
// ---------------------------------------------------------------------------
__global__ __launch_bounds__(NTHR, 2) void ssm_main(
    const float* __restrict__ x, const float* __restrict__ Wf,
    const uint* __restrict__ Fr, const float* __restrict__ Bb,
    float* __restrict__ part)
{
  extern __shared__ uint lds[];
  float*  ldsF = (float*)lds;
  ushort* ldsH = (ushort*)lds;
  const int tid = threadIdx.x;
  const int lane = tid & 63, wid = tid >> 6;
  const int li = lane & 15, q4 = (lane >> 4) & 3;
  const int blk = blockIdx.x;
  const int bb = blk >> 6;                 // 64 chunks per sequence
  const int s0base = (blk & 63) * TOUT;

  // ---- stage x -> fp16 LDS rows [192][34] ----
  {
    const float4* xg4 = (const float4*)(x + (size_t)bb * S_ * DIN);
    #pragma unroll
    for (int k = 0; k < 8; ++k) {
      const int idx = k * NTHR + tid;
      const int tok = idx >> 4, c4 = idx & 15;
      const int lt = s0base - NWARM + tok;
      float4 v = make_float4(0.f, 0.f, 0.f, 0.f);
      if (lt >= 0) v = xg4[lt * 16 + c4];
      lds[LX + tok*34 + 2*c4]     = pack2(v.x, v.y);
      lds[LX + tok*34 + 2*c4 + 1] = pack2(v.z, v.w);
    }
  }
  __syncthreads();

  // ---- X A-frags (resident) ----
  uv4 xf[2][2];
  #pragma unroll
  for (int m = 0; m < 2; ++m)
    #pragma unroll
    for (int k = 0; k < 2; ++k) {
      const uint* p = lds + LX + (wid*32 + m*16 + li)*34 + k*16 + q4*4;
      uv4 v; v[0] = p[0]; v[1] = p[1]; v[2] = p[2]; v[3] = p[3];
      xf[m][k] = v;
    }

  // ---- nq0 = g0 + 2 gx.x + x^T G x ----
  {
    float val[2][4] = {{0,0,0,0},{0,0,0,0}};
    #pragma unroll
    for (int nt = 0; nt < 4; ++nt) {
      const float gxv = 2.f * Wf[OFF_GX + nt*16 + li];
      const uv4 bg0 = ldB(Fr, 0*4 + nt, lane);
      const uv4 bg1 = ldB(Fr, 1*4 + nt, lane);
      #pragma unroll
      for (int m = 0; m < 2; ++m) {
        f32x4 c = {gxv, gxv, gxv, gxv};
        c = MF(xf[m][0], bg0, c);
        c = MF(xf[m][1], bg1, c);
        #pragma unroll
        for (int r = 0; r < 4; ++r) {
          const int tk = wid*32 + m*16 + q4*4 + r;
          const float xv = h2f(ldsH[tk*68 + nt*16 + li]);
          val[m][r] = fmaf(c[r], xv, val[m][r]);
        }
      }
    }
    const float g0 = Wf[OFF_G0];
    #pragma unroll
    for (int m = 0; m < 2; ++m)
      #pragma unroll
      for (int r = 0; r < 4; ++r) {
        float v = val[m][r];
        v += __shfl_xor(v, 1, 64); v += __shfl_xor(v, 2, 64);
        v += __shfl_xor(v, 4, 64); v += __shfl_xor(v, 8, 64);
        if (li == 0) ldsF[LNQ + wid*32 + m*16 + q4*4 + r] = g0 + v;
      }
  }
  __syncthreads();

  // ---- layers ----
  uv4 sf0[2], sf1[2], sf2[2], sf3[2];
  layer_mfma<0>(tid, lane, wid, s0base, lds, Wf, Fr, Bb, xf, sf0, sf1, sf2, sf3);
  layer_mfma<1>(tid, lane, wid, s0base, lds, Wf, Fr, Bb, xf, sf0, sf1, sf2, sf3);
  layer_mfma<2>(tid, lane, wid, s0base, lds, Wf, Fr, Bb, xf, sf0, sf1, sf2, sf3);
  layer_mfma<3>(tid, lane, wid, s0base, lds, Wf, Fr, Bb, xf, sf0, sf1, sf2, sf3);

  // ---- final r + block partial sums (6 narrow passes over dead x region) ----
  float rr = 0.f;
  if (tid >= NWARM && tid < PIPE)
    rr = 1.0f / (sqrtf(fmaxf(ldsF[LNQ + tid], 0.f)) * 0.0625f + 1e-8f);
  const int jj = tid - NWARM;             // 0..127 for output tokens
  float* pf = (float*)lds;                // overlays x (dead)

  // pass A1: [r | x0..31 * r]
  if (tid >= NWARM && tid < PIPE) {
    pf[jj*33] = rr;
    const float4* xr4 = (const float4*)(x + ((size_t)bb * S_ + (size_t)(s0base + jj)) * DIN);
    #pragma unroll
    for (int c4 = 0; c4 < 8; ++c4) {
      const float4 v = xr4[c4];
      pf[jj*33 + 1 + 4*c4] = v.x * rr; pf[jj*33 + 2 + 4*c4] = v.y * rr;
      pf[jj*33 + 3 + 4*c4] = v.z * rr; pf[jj*33 + 4 + 4*c4] = v.w * rr;
    }
  }
  __syncthreads();
  if (tid < 33) { float s = 0.f;
    for (int k = 0; k < TOUT; ++k) s += pf[k*33 + tid];
    part[blk*193 + tid] = s; }
  __syncthreads();
  // pass A2: x32..63 * r
  if (tid >= NWARM && tid < PIPE) {
    const float4* xr4 = (const float4*)(x + ((size_t)bb * S_ + (size_t)(s0base + jj)) * DIN);
    #pragma unroll
    for (int c4 = 8; c4 < 16; ++c4) {
      const float4 v = xr4[c4];
      const int o = 4*c4 - 32;
      pf[jj*33 + o]     = v.x * rr; pf[jj*33 + o + 1] = v.y * rr;
      pf[jj*33 + o + 2] = v.z * rr; pf[jj*33 + o + 3] = v.w * rr;
    }
  }
  __syncthreads();
  if (tid < 32) { float s = 0.f;
    for (int k = 0; k < TOUT; ++k) s += pf[k*33 + tid];
    part[blk*193 + 33 + tid] = s; }
  __syncthreads();
  // passes B..E: s_l * r
  for (int l = 0; l < 4; ++l) {
    if (tid >= NWARM && tid < PIPE) {
      #pragma unroll
      for (int m2 = 0; m2 < 16; ++m2) {
        const uint w = lds[LS0 + l*3264 + tid*17 + m2];
        pf[jj*33 + 2*m2]     = h2f((ushort)(w & 0xffffu)) * rr;
        pf[jj*33 + 2*m2 + 1] = h2f((ushort)(w >> 16)) * rr;
      }
    }
    __syncthreads();
    if (tid < 32) { float s = 0.f;
      for (int k = 0; k < TOUT; ++k) s += pf[k*33 + tid];
      part[blk*193 + 65 + l*32 + tid] = s; }
    __syncthreads();
  }
}

// ---------------------------------------------------------------------------
// Final: reduce partials (64 rows/batch, 4-way ILP), mean, classifier MLP.
// ---------------------------------------------------------------------------
__global__ __launch_bounds__(256) void ssm_final(
    const float* __restrict__ part,
    const float* __restrict__ in_w, const float* __restrict__ in_b,
    const float* __restrict__ Cw, const float* __restrict__ Cb,
    const float* __restrict__ fsc,
    const float* __restrict__ w1, const float* __restrict__ b1,
    const float* __restrict__ w2, const float* __restrict__ b2,
    float* __restrict__ out)
{
  const int b = blockIdx.x, t = threadIdx.x;
  __shared__ float red[193];
  __shared__ float meanv[DM];
  __shared__ float h1[DM];
  if (t < 193) {
    float a0 = 0.f, a1 = 0.f, a2 = 0.f, a3 = 0.f;
    const float* pp = part + (size_t)b * 64 * 193 + t;
    for (int k = 0; k < 64; k += 4) {
      a0 += pp[(k + 0) * 193]; a1 += pp[(k + 1) * 193];
      a2 += pp[(k + 2) * 193]; a3 += pp[(k + 3) * 193];
    }
    red[t] = (a0 + a1) + (a2 + a3);
  }
  __syncthreads();
  {
    const float rho = red[0];
    float m = in_b[t] * rho;
    #pragma unroll 4
    for (int i = 0; i < 64; ++i) m = fmaf(in_w[t*64 + i], red[1 + i], m);
    for (int l = 0; l < NL; ++l) {
      #pragma unroll 4
      for (int n = 0; n < 32; ++n)
        m = fmaf(Cw[(l*DM + t)*NS + n], red[65 + l*32 + n], m);
      m = fmaf(Cb[l*DM + t], rho, m);
    }
    meanv[t] = fsc[t] * m * (1.0f / (float)S_);
  }
  __syncthreads();
  {
    float z = b1[t];
    for (int e = 0; e < DM; ++e) z = fmaf(w1[t*DM + e], meanv[e], z);
    h1[t] = z / (1.0f + expf(-z));
  }
  __syncthreads();
  if (t < 10) {
    float lg = b2[t];
    for (int e = 0; e < DM; ++e) lg = fmaf(w2[t*DM + e], h1[e], lg);
    out[b*10 + t] = lg;
  }
}

// ---------------------------------------------------------------------------
extern "C" void kernel_launch(void* const* d_in, const int* in_sizes, int n_in,
                              void* d_out, int out_size, void* d_ws, size_t ws_size,
                              hipStream_t stream)
{
  const float* x    = (const float*)d_in[0];
  const float* in_w = (const float*)d_in[1];
  const float* in_b = (const float*)d_in[2];
  const float* logA = (const float*)d_in[3];
  const float* Bw   = (const float*)d_in[4];
  const float* Bb   = (const float*)d_in[5];
  const float* Cw   = (const float*)d_in[6];
  const float* Cb   = (const float*)d_in[7];
  const float* nsc  = (const float*)d_in[8];
  const float* fsc  = (const float*)d_in[9];
  const float* w1   = (const float*)d_in[10];
  const float* b1   = (const float*)d_in[11];
  const float* w2   = (const float*)d_in[12];
  const float* b2   = (const float*)d_in[13];
  float* out  = (float*)d_out;
  float* wsf  = (float*)d_ws;
  uint*  Fr   = (uint*)(wsf + WS_FRAG);
  float* part = wsf + WS_PART;
  float* xp   = wsf + WS_XP;
  (void)in_sizes; (void)n_in; (void)out_size; (void)ws_size;

  ssm_xpose<<<196, 256, 0, stream>>>(in_w, Cw, in_b, Cb, xp);
  ssm_prep<<<(PRE_N + 3) / 4, 256, 0, stream>>>(logA, Bw, nsc, in_b, Cb, xp,
                                                wsf, (ushort*)Fr);
  ssm_main<<<NBLK, NTHR, LDSN * sizeof(uint), stream>>>(x, wsf, Fr, Bb, part);
  ssm_final<<<B_, 256, 0, stream>>>(part, in_w, in_b, Cw, Cb, fsc, w1, b1, w2, b2, out);
}